// Round 1
// baseline (857.682 us; speedup 1.0000x reference)
//
#include <hip/hip_runtime.h>
#include <math.h>

#define N_NODES 20000
#define DEG 32
#define F_IN 142
#define HD 128
#define NHEAD 4
#define DHEAD 32
#define N_CLS 2

// eval-mode BatchNorm1d scale: 1/sqrt(1 + 1e-5)
#define BN_SCALE 0.9999950000374997f
// 1/sqrt(32)
#define INV_SQRT_D 0.17677669529663687f

__device__ __forceinline__ float blockReduceSum128(float val, float* sdata, int tid) {
    sdata[tid] = val;
    __syncthreads();
    #pragma unroll
    for (int s = 64; s > 0; s >>= 1) {
        if (tid < s) sdata[tid] += sdata[tid + s];
        __syncthreads();
    }
    float r = sdata[0];
    __syncthreads();   // safe reuse of sdata by caller
    return r;
}

// ---- Kernel A: t = PReLU(BN(feat@W1 + b1 + label_emb[labels]@W2 + b2)) ----
__global__ void kA(const float* __restrict__ feat, const float* __restrict__ lemb,
                   const int* __restrict__ labels,
                   const float* __restrict__ W1, const float* __restrict__ b1,
                   const float* __restrict__ W2, const float* __restrict__ b2,
                   const float* __restrict__ bng, const float* __restrict__ bnb,
                   const float* __restrict__ a3,
                   float* __restrict__ tOut) {
    __shared__ float sf[F_IN];
    __shared__ float sl[F_IN];
    int n = blockIdx.x, c = threadIdx.x;
    int lab = labels[n];
    for (int f = c; f < F_IN; f += HD) {
        sf[f] = feat[n * F_IN + f];
        sl[f] = lemb[lab * F_IN + f];
    }
    __syncthreads();
    float acc = b1[c] + b2[c];
    for (int f = 0; f < F_IN; ++f)
        acc += sf[f] * W1[f * HD + c] + sl[f] * W2[f * HD + c];
    float y = acc * BN_SCALE * bng[c] + bnb[c];
    float a = a3[0];
    tOut[n * HD + c] = (y >= 0.f) ? y : a * y;
}

// ---- Kernel B: h = feat + (t @ W3 + b3)   (W3: [128,142]) ----
__global__ void kB(const float* __restrict__ t, const float* __restrict__ feat,
                   const float* __restrict__ W3, const float* __restrict__ b3,
                   float* __restrict__ h) {
    __shared__ float st[HD];
    int n = blockIdx.x, c = threadIdx.x;
    if (c < HD) st[c] = t[n * HD + c];
    __syncthreads();
    if (c < F_IN) {
        float acc = b3[c];
        for (int k = 0; k < HD; ++k) acc += st[k] * W3[k * F_IN + c];
        h[n * F_IN + c] = feat[n * F_IN + c] + acc;
    }
}

// ---- Kernel C: q/k/v/skip = h @ W* + b*  (fused 4 projections) ----
__global__ void kC(const float* __restrict__ h, int fin,
                   const float* __restrict__ Wq, const float* __restrict__ bq,
                   const float* __restrict__ Wk, const float* __restrict__ bk,
                   const float* __restrict__ Wv, const float* __restrict__ bv,
                   const float* __restrict__ Ws, const float* __restrict__ bs,
                   float* __restrict__ q, float* __restrict__ k,
                   float* __restrict__ v, float* __restrict__ s) {
    __shared__ float sh[F_IN];
    int n = blockIdx.x, c = threadIdx.x;
    for (int f = c; f < fin; f += HD) sh[f] = h[n * fin + f];
    __syncthreads();
    float aq = bq[c], ak = bk[c], av = bv[c], asv = bs[c];
    for (int f = 0; f < fin; ++f) {
        float hv = sh[f];
        aq  += hv * Wq[f * HD + c];
        ak  += hv * Wk[f * HD + c];
        av  += hv * Wv[f * HD + c];
        asv += hv * Ws[f * HD + c];
    }
    int o = n * HD + c;
    q[o] = aq; k[o] = ak; v[o] = av; s[o] = asv;
}

// ---- Kernel D: per-node edge-softmax attention (exploits dst = repeat(arange(N),32)) ----
__global__ void kD(const float* __restrict__ q, const float* __restrict__ k,
                   const float* __restrict__ v, const int* __restrict__ esrc,
                   float* __restrict__ agg) {
    __shared__ float sk[HD];
    __shared__ int ssrc[DEG];
    __shared__ float sa[NHEAD][DEG];
    int n = blockIdx.x, t = threadIdx.x;
    sk[t] = k[n * HD + t];
    if (t < DEG) ssrc[t] = esrc[n * DEG + t];
    __syncthreads();

    int hh = t >> 5;       // head 0..3
    int e  = t & 31;       // edge 0..31
    int sNode = ssrc[e];
    // score[e,h] = dot(q[src,h,:], k[n,h,:]) / sqrt(D)
    const float4* qp4 = (const float4*)(q + (size_t)sNode * HD + hh * DHEAD);
    const float4* kp4 = (const float4*)(sk + hh * DHEAD);
    float sc = 0.f;
    #pragma unroll
    for (int d4 = 0; d4 < DHEAD / 4; ++d4) {
        float4 qq = qp4[d4];
        float4 kk = kp4[d4];
        sc += qq.x * kk.x + qq.y * kk.y + qq.z * kk.z + qq.w * kk.w;
    }
    sc *= INV_SQRT_D;
    // softmax across the 32 edges (32-lane subgroup shuffle)
    float m = sc;
    #pragma unroll
    for (int off = 16; off > 0; off >>= 1)
        m = fmaxf(m, __shfl_xor(m, off, 32));
    float p = expf(sc - m);
    float ssum = p;
    #pragma unroll
    for (int off = 16; off > 0; off >>= 1)
        ssum += __shfl_xor(ssum, off, 32);
    sa[hh][e] = p / ssum;
    __syncthreads();

    // agg[n,h,d] = sum_e sa[h,e] * v[src[e],h,d]   (thread t -> (head hh, dim d))
    int d = t & 31;
    float acc = 0.f;
    for (int e2 = 0; e2 < DEG; ++e2)
        acc += sa[hh][e2] * v[(size_t)ssrc[e2] * HD + hh * DHEAD + d];
    agg[n * HD + t] = acc;
}

// ---- Kernel E: scalar gate + gated mix + LayerNorm + PReLU ----
__global__ void kE(const float* __restrict__ skip, const float* __restrict__ agg,
                   const float* __restrict__ Wg, const float* __restrict__ bg,
                   const float* __restrict__ lng, const float* __restrict__ lnb,
                   const float* __restrict__ ac,
                   float* __restrict__ hout) {
    __shared__ float red[HD];
    int n = blockIdx.x, c = threadIdx.x;
    float sk = skip[n * HD + c], ag = agg[n * HD + c];
    float part = sk * Wg[c] + ag * Wg[HD + c] + (sk - ag) * Wg[2 * HD + c];
    float z = blockReduceSum128(part, red, c) + bg[0];
    float g = 1.f / (1.f + expf(-z));
    float r = g * sk + (1.f - g) * ag;
    float mean = blockReduceSum128(r, red, c) * (1.f / HD);
    float dv = r - mean;
    float var = blockReduceSum128(dv * dv, red, c) * (1.f / HD);
    float y = dv * rsqrtf(var + 1e-5f) * lng[c] + lnb[c];
    float a = ac[0];
    hout[n * HD + c] = (y >= 0.f) ? y : a * y;
}

// ---- Kernel F: out = PReLU(BN(h@W4 + b4)) @ W5 + b5 ----
__global__ void kF(const float* __restrict__ h, const float* __restrict__ W4,
                   const float* __restrict__ b4, const float* __restrict__ bng,
                   const float* __restrict__ bnb, const float* __restrict__ a5,
                   const float* __restrict__ W5, const float* __restrict__ b5,
                   float* __restrict__ out) {
    __shared__ float shh[HD];
    __shared__ float red[HD];
    int n = blockIdx.x, c = threadIdx.x;
    shh[c] = h[n * HD + c];
    __syncthreads();
    float acc = b4[c];
    for (int k2 = 0; k2 < HD; ++k2) acc += shh[k2] * W4[k2 * HD + c];
    float y = acc * BN_SCALE * bng[c] + bnb[c];
    float a = a5[0];
    y = (y >= 0.f) ? y : a * y;
    float o0 = blockReduceSum128(y * W5[c * N_CLS + 0], red, c);
    float o1 = blockReduceSum128(y * W5[c * N_CLS + 1], red, c);
    if (c == 0) {
        out[n * N_CLS + 0] = o0 + b5[0];
        out[n * N_CLS + 1] = o1 + b5[1];
    }
}

extern "C" void kernel_launch(void* const* d_in, const int* in_sizes, int n_in,
                              void* d_out, int out_size, void* d_ws, size_t ws_size,
                              hipStream_t stream) {
    const float* feat  = (const float*)d_in[0];
    const float* lemb  = (const float*)d_in[1];
    const float* W1    = (const float*)d_in[2];
    const float* b1    = (const float*)d_in[3];
    const float* W2    = (const float*)d_in[4];
    const float* b2    = (const float*)d_in[5];
    const float* bn0g  = (const float*)d_in[6];
    const float* bn0b  = (const float*)d_in[7];
    const float* a3    = (const float*)d_in[8];
    const float* W3    = (const float*)d_in[9];
    const float* b3    = (const float*)d_in[10];
    // conv layer params at 11 + l*12
    const float* aconv = (const float*)d_in[35];
    const float* W4    = (const float*)d_in[36];
    const float* b4    = (const float*)d_in[37];
    const float* bn1g  = (const float*)d_in[38];
    const float* bn1b  = (const float*)d_in[39];
    const float* a5    = (const float*)d_in[40];
    const float* W5    = (const float*)d_in[41];
    const float* b5    = (const float*)d_in[42];
    const int*   labels = (const int*)d_in[43];
    const int*   esrc   = (const int*)d_in[44];
    // d_in[45] edge_dst: known structure repeat(arange(N), DEG) — consumed implicitly

    float* ws  = (float*)d_ws;
    float* bh  = ws;                          // [N,142] h (layer-0 input)
    float* bq  = bh  + (size_t)N_NODES * F_IN;// [N,128] t, then q
    float* bk  = bq  + (size_t)N_NODES * HD;
    float* bv  = bk  + (size_t)N_NODES * HD;
    float* bs  = bv  + (size_t)N_NODES * HD;
    float* bag = bs  + (size_t)N_NODES * HD;
    float* bh2 = bag + (size_t)N_NODES * HD;  // [N,128] conv output
    float* out = (float*)d_out;

    dim3 gN(N_NODES);
    kA<<<gN, HD, 0, stream>>>(feat, lemb, labels, W1, b1, W2, b2, bn0g, bn0b, a3, bq);
    kB<<<gN, 192, 0, stream>>>(bq, feat, W3, b3, bh);

    // conv layer 0 (fin = 142)
    kC<<<gN, HD, 0, stream>>>(bh, F_IN,
                              (const float*)d_in[11], (const float*)d_in[12],
                              (const float*)d_in[13], (const float*)d_in[14],
                              (const float*)d_in[15], (const float*)d_in[16],
                              (const float*)d_in[17], (const float*)d_in[18],
                              bq, bk, bv, bs);
    kD<<<gN, HD, 0, stream>>>(bq, bk, bv, esrc, bag);
    kE<<<gN, HD, 0, stream>>>(bs, bag, (const float*)d_in[19], (const float*)d_in[20],
                              (const float*)d_in[21], (const float*)d_in[22], aconv, bh2);

    // conv layer 1 (fin = 128)
    kC<<<gN, HD, 0, stream>>>(bh2, HD,
                              (const float*)d_in[23], (const float*)d_in[24],
                              (const float*)d_in[25], (const float*)d_in[26],
                              (const float*)d_in[27], (const float*)d_in[28],
                              (const float*)d_in[29], (const float*)d_in[30],
                              bq, bk, bv, bs);
    kD<<<gN, HD, 0, stream>>>(bq, bk, bv, esrc, bag);
    kE<<<gN, HD, 0, stream>>>(bs, bag, (const float*)d_in[31], (const float*)d_in[32],
                              (const float*)d_in[33], (const float*)d_in[34], aconv, bh2);

    kF<<<gN, HD, 0, stream>>>(bh2, W4, b4, bn1g, bn1b, a5, W5, b5, out);
}

// Round 2
// 504.280 us; speedup vs baseline: 1.7008x; 1.7008x over previous
//
#include <hip/hip_runtime.h>
#include <math.h>

#define N_NODES 20000
#define DEG 32
#define F_IN 142
#define HD 128
#define NHEAD 4
#define DHEAD 32
#define N_CLS 2

// eval-mode BatchNorm1d scale: 1/sqrt(1 + 1e-5)
#define BN_SCALE 0.9999950000374997f
// 1/sqrt(32)
#define INV_SQRT_D 0.17677669529663687f

// ---------------- tiny precompute: E[l] = lemb[l] @ W2 + b1 + b2 (l=0..2) ----------------
__global__ void kE0(const float* __restrict__ lemb, const float* __restrict__ W2,
                    const float* __restrict__ b1, const float* __restrict__ b2,
                    float* __restrict__ E) {
    __shared__ float sl[F_IN];
    int l = blockIdx.x, c = threadIdx.x;
    for (int f = c; f < F_IN; f += HD) sl[f] = lemb[l * F_IN + f];
    __syncthreads();
    float acc = b1[c] + b2[c];
    for (int f = 0; f < F_IN; ++f) acc += sl[f] * W2[f * HD + c];
    E[l * HD + c] = acc;
}

// ---------------- shared tiled-GEMM core: 32 rows x 128 cols, K-chunked weights ----------------
// sA: [32*K] staged A tile. sW: [16*128] weight chunk. Each thread: 4 rows x 4 cols.
template<int K>
__device__ __forceinline__ void gemm_acc(const float* __restrict__ W,
                                         const float* sA, float* sW,
                                         float acc[4][4], int tid, int tr, int tc) {
    int k0 = 0;
    for (; k0 + 16 <= K; k0 += 16) {
        __syncthreads();
        #pragma unroll
        for (int i = 0; i < 8; ++i)            // 16*128/256 = 8 per thread, coalesced
            sW[tid + i * 256] = W[k0 * HD + tid + i * 256];
        __syncthreads();
        #pragma unroll
        for (int kk = 0; kk < 16; ++kk) {
            const float4 wv = *(const float4*)(sW + kk * HD + tc * 4);
            #pragma unroll
            for (int i = 0; i < 4; ++i) {
                const float av = sA[(tr * 4 + i) * K + k0 + kk];
                acc[i][0] = fmaf(av, wv.x, acc[i][0]);
                acc[i][1] = fmaf(av, wv.y, acc[i][1]);
                acc[i][2] = fmaf(av, wv.z, acc[i][2]);
                acc[i][3] = fmaf(av, wv.w, acc[i][3]);
            }
        }
    }
    if (k0 < K) {
        const int kb = K - k0;
        __syncthreads();
        for (int i = tid; i < kb * HD; i += 256)
            sW[i] = W[k0 * HD + i];
        __syncthreads();
        for (int kk = 0; kk < kb; ++kk) {
            const float4 wv = *(const float4*)(sW + kk * HD + tc * 4);
            #pragma unroll
            for (int i = 0; i < 4; ++i) {
                const float av = sA[(tr * 4 + i) * K + k0 + kk];
                acc[i][0] = fmaf(av, wv.x, acc[i][0]);
                acc[i][1] = fmaf(av, wv.y, acc[i][1]);
                acc[i][2] = fmaf(av, wv.z, acc[i][2]);
                acc[i][3] = fmaf(av, wv.w, acc[i][3]);
            }
        }
    }
}

// ---------------- kA: t = PReLU(BN(feat@W1 + E[label])) ----------------
template<int K>
__global__ __launch_bounds__(256) void kA_t(const float* __restrict__ A,
        const int* __restrict__ labels, const float* __restrict__ E,
        const float* __restrict__ W1,
        const float* __restrict__ bng, const float* __restrict__ bnb,
        const float* __restrict__ a3, float* __restrict__ tOut) {
    __shared__ float sA[32 * K];
    __shared__ float sW[16 * HD];
    __shared__ int sLab[32];
    const int tid = threadIdx.x, tr = tid >> 5, tc = tid & 31;
    const int row0 = blockIdx.x * 32;
    for (int i = tid; i < 32 * K; i += 256) sA[i] = A[(size_t)row0 * K + i];
    if (tid < 32) sLab[tid] = labels[row0 + tid];
    float acc[4][4] = {};
    gemm_acc<K>(W1, sA, sW, acc, tid, tr, tc);
    const int c = tc * 4;
    const float4 g4 = *(const float4*)(bng + c);
    const float4 bb4 = *(const float4*)(bnb + c);
    const float al = a3[0];
    #pragma unroll
    for (int i = 0; i < 4; ++i) {
        const int r = tr * 4 + i;
        const float4 e4 = *(const float4*)(E + sLab[r] * HD + c);
        float4 o;
        o.x = (acc[i][0] + e4.x) * BN_SCALE * g4.x + bb4.x;
        o.y = (acc[i][1] + e4.y) * BN_SCALE * g4.y + bb4.y;
        o.z = (acc[i][2] + e4.z) * BN_SCALE * g4.z + bb4.z;
        o.w = (acc[i][3] + e4.w) * BN_SCALE * g4.w + bb4.w;
        o.x = (o.x >= 0.f) ? o.x : al * o.x;
        o.y = (o.y >= 0.f) ? o.y : al * o.y;
        o.z = (o.z >= 0.f) ? o.z : al * o.z;
        o.w = (o.w >= 0.f) ? o.w : al * o.w;
        *(float4*)(tOut + (size_t)(row0 + r) * HD + c) = o;
    }
}

// ---------------- kB: h = feat + t @ W3 + b3   (16-row tile, col-per-thread) ----------------
__global__ __launch_bounds__(192) void kB_t(const float* __restrict__ t,
        const float* __restrict__ feat, const float* __restrict__ W3,
        const float* __restrict__ b3, float* __restrict__ h) {
    __shared__ float sA[16 * HD];
    const int tid = threadIdx.x;
    const int row0 = blockIdx.x * 16;
    for (int i = tid; i < 16 * HD; i += 192) sA[i] = t[(size_t)row0 * HD + i];
    __syncthreads();
    const int c = (tid < F_IN) ? tid : (F_IN - 1);   // clamp to avoid OOB, no divergence
    float acc[16] = {};
    for (int k0 = 0; k0 < HD; k0 += 8) {
        float w[8];
        #pragma unroll
        for (int kk = 0; kk < 8; ++kk) w[kk] = W3[(k0 + kk) * F_IN + c];
        #pragma unroll
        for (int r = 0; r < 16; ++r) {
            const float4 a0 = *(const float4*)(sA + r * HD + k0);
            const float4 a1 = *(const float4*)(sA + r * HD + k0 + 4);
            acc[r] = fmaf(a0.x, w[0], acc[r]);
            acc[r] = fmaf(a0.y, w[1], acc[r]);
            acc[r] = fmaf(a0.z, w[2], acc[r]);
            acc[r] = fmaf(a0.w, w[3], acc[r]);
            acc[r] = fmaf(a1.x, w[4], acc[r]);
            acc[r] = fmaf(a1.y, w[5], acc[r]);
            acc[r] = fmaf(a1.z, w[6], acc[r]);
            acc[r] = fmaf(a1.w, w[7], acc[r]);
        }
    }
    if (tid < F_IN) {
        const float bb = b3[c];
        #pragma unroll
        for (int r = 0; r < 16; ++r)
            h[(size_t)(row0 + r) * F_IN + c] =
                feat[(size_t)(row0 + r) * F_IN + c] + acc[r] + bb;
    }
}

// ---------------- kC: fused q/k/v/skip projections, one matrix per blockIdx.y ----------------
template<int K>
__global__ __launch_bounds__(256) void kC_t(const float* __restrict__ A,
        const float* __restrict__ Wq, const float* __restrict__ Wk,
        const float* __restrict__ Wv, const float* __restrict__ Ws,
        const float* __restrict__ bq, const float* __restrict__ bk,
        const float* __restrict__ bv, const float* __restrict__ bs,
        float* __restrict__ q, float* __restrict__ k,
        float* __restrict__ v, float* __restrict__ s) {
    __shared__ float sA[32 * K];
    __shared__ float sW[16 * HD];
    const float* Wt[4] = {Wq, Wk, Wv, Ws};
    const float* bt[4] = {bq, bk, bv, bs};
    float* ot[4] = {q, k, v, s};
    const int m = blockIdx.y;
    const float* W = Wt[m];
    const float* bias = bt[m];
    float* out = ot[m];
    const int tid = threadIdx.x, tr = tid >> 5, tc = tid & 31;
    const int row0 = blockIdx.x * 32;
    for (int i = tid; i < 32 * K; i += 256) sA[i] = A[(size_t)row0 * K + i];
    float acc[4][4] = {};
    gemm_acc<K>(W, sA, sW, acc, tid, tr, tc);
    const int c = tc * 4;
    const float4 b4v = *(const float4*)(bias + c);
    #pragma unroll
    for (int i = 0; i < 4; ++i) {
        const int r = tr * 4 + i;
        float4 o;
        o.x = acc[i][0] + b4v.x;
        o.y = acc[i][1] + b4v.y;
        o.z = acc[i][2] + b4v.z;
        o.w = acc[i][3] + b4v.w;
        *(float4*)(out + (size_t)(row0 + r) * HD + c) = o;
    }
}

// ---------------- kD: per-node edge-softmax attention ----------------
__global__ void kD(const float* __restrict__ q, const float* __restrict__ k,
                   const float* __restrict__ v, const int* __restrict__ esrc,
                   float* __restrict__ agg) {
    __shared__ float sk[HD];
    __shared__ int ssrc[DEG];
    __shared__ float sa[NHEAD][DEG];
    int n = blockIdx.x, t = threadIdx.x;
    sk[t] = k[n * HD + t];
    if (t < DEG) ssrc[t] = esrc[n * DEG + t];
    __syncthreads();

    int hh = t >> 5;
    int e  = t & 31;
    int sNode = ssrc[e];
    const float4* qp4 = (const float4*)(q + (size_t)sNode * HD + hh * DHEAD);
    const float4* kp4 = (const float4*)(sk + hh * DHEAD);
    float sc = 0.f;
    #pragma unroll
    for (int d4 = 0; d4 < DHEAD / 4; ++d4) {
        float4 qq = qp4[d4];
        float4 kk = kp4[d4];
        sc += qq.x * kk.x + qq.y * kk.y + qq.z * kk.z + qq.w * kk.w;
    }
    sc *= INV_SQRT_D;
    float m = sc;
    #pragma unroll
    for (int off = 16; off > 0; off >>= 1)
        m = fmaxf(m, __shfl_xor(m, off, 32));
    float p = expf(sc - m);
    float ssum = p;
    #pragma unroll
    for (int off = 16; off > 0; off >>= 1)
        ssum += __shfl_xor(ssum, off, 32);
    sa[hh][e] = p / ssum;
    __syncthreads();

    int d = t & 31;
    float acc = 0.f;
    for (int e2 = 0; e2 < DEG; ++e2)
        acc += sa[hh][e2] * v[(size_t)ssrc[e2] * HD + hh * DHEAD + d];
    agg[n * HD + t] = acc;
}

__device__ __forceinline__ float blockReduceSum128(float val, float* sdata, int tid) {
    sdata[tid] = val;
    __syncthreads();
    #pragma unroll
    for (int s = 64; s > 0; s >>= 1) {
        if (tid < s) sdata[tid] += sdata[tid + s];
        __syncthreads();
    }
    float r = sdata[0];
    __syncthreads();
    return r;
}

// ---------------- kE: scalar gate + gated mix + LayerNorm + PReLU ----------------
__global__ void kE(const float* __restrict__ skip, const float* __restrict__ agg,
                   const float* __restrict__ Wg, const float* __restrict__ bg,
                   const float* __restrict__ lng, const float* __restrict__ lnb,
                   const float* __restrict__ ac,
                   float* __restrict__ hout) {
    __shared__ float red[HD];
    int n = blockIdx.x, c = threadIdx.x;
    float sk = skip[n * HD + c], ag = agg[n * HD + c];
    float part = sk * Wg[c] + ag * Wg[HD + c] + (sk - ag) * Wg[2 * HD + c];
    float z = blockReduceSum128(part, red, c) + bg[0];
    float g = 1.f / (1.f + expf(-z));
    float r = g * sk + (1.f - g) * ag;
    float mean = blockReduceSum128(r, red, c) * (1.f / HD);
    float dv = r - mean;
    float var = blockReduceSum128(dv * dv, red, c) * (1.f / HD);
    float y = dv * rsqrtf(var + 1e-5f) * lng[c] + lnb[c];
    float a = ac[0];
    hout[n * HD + c] = (y >= 0.f) ? y : a * y;
}

// ---------------- kF: out = PReLU(BN(h@W4 + b4)) @ W5 + b5, tiled ----------------
__global__ __launch_bounds__(256) void kF_t(const float* __restrict__ A,
        const float* __restrict__ W4, const float* __restrict__ b4,
        const float* __restrict__ bng, const float* __restrict__ bnb,
        const float* __restrict__ a5, const float* __restrict__ W5,
        const float* __restrict__ b5, float* __restrict__ out) {
    __shared__ float sA[32 * HD];
    __shared__ float sW[16 * HD];
    const int tid = threadIdx.x, tr = tid >> 5, tc = tid & 31;
    const int row0 = blockIdx.x * 32;
    for (int i = tid; i < 32 * HD; i += 256) sA[i] = A[(size_t)row0 * HD + i];
    float acc[4][4] = {};
    gemm_acc<HD>(W4, sA, sW, acc, tid, tr, tc);
    const int c = tc * 4;
    const float4 bb = *(const float4*)(b4 + c);
    const float4 g4 = *(const float4*)(bng + c);
    const float4 bn4 = *(const float4*)(bnb + c);
    const float al = a5[0];
    // W5 columns for classes 0/1 at cols c..c+3: flat W5[c*2 .. c*2+7]
    const float4 w5a = *(const float4*)(W5 + c * 2);
    const float4 w5b = *(const float4*)(W5 + c * 2 + 4);
    const float b50 = b5[0], b51 = b5[1];
    #pragma unroll
    for (int i = 0; i < 4; ++i) {
        float y0 = (acc[i][0] + bb.x) * BN_SCALE * g4.x + bn4.x;
        float y1 = (acc[i][1] + bb.y) * BN_SCALE * g4.y + bn4.y;
        float y2 = (acc[i][2] + bb.z) * BN_SCALE * g4.z + bn4.z;
        float y3 = (acc[i][3] + bb.w) * BN_SCALE * g4.w + bn4.w;
        y0 = (y0 >= 0.f) ? y0 : al * y0;
        y1 = (y1 >= 0.f) ? y1 : al * y1;
        y2 = (y2 >= 0.f) ? y2 : al * y2;
        y3 = (y3 >= 0.f) ? y3 : al * y3;
        float p0 = y0 * w5a.x + y1 * w5a.z + y2 * w5b.x + y3 * w5b.z;
        float p1 = y0 * w5a.y + y1 * w5a.w + y2 * w5b.y + y3 * w5b.w;
        #pragma unroll
        for (int off = 16; off > 0; off >>= 1) {
            p0 += __shfl_xor(p0, off, 32);
            p1 += __shfl_xor(p1, off, 32);
        }
        if (tc == 0) {
            const int r = row0 + tr * 4 + i;
            out[r * N_CLS + 0] = p0 + b50;
            out[r * N_CLS + 1] = p1 + b51;
        }
    }
}

extern "C" void kernel_launch(void* const* d_in, const int* in_sizes, int n_in,
                              void* d_out, int out_size, void* d_ws, size_t ws_size,
                              hipStream_t stream) {
    const float* feat  = (const float*)d_in[0];
    const float* lemb  = (const float*)d_in[1];
    const float* W1    = (const float*)d_in[2];
    const float* b1    = (const float*)d_in[3];
    const float* W2    = (const float*)d_in[4];
    const float* b2    = (const float*)d_in[5];
    const float* bn0g  = (const float*)d_in[6];
    const float* bn0b  = (const float*)d_in[7];
    const float* a3    = (const float*)d_in[8];
    const float* W3    = (const float*)d_in[9];
    const float* b3    = (const float*)d_in[10];
    const float* aconv = (const float*)d_in[35];
    const float* W4    = (const float*)d_in[36];
    const float* b4    = (const float*)d_in[37];
    const float* bn1g  = (const float*)d_in[38];
    const float* bn1b  = (const float*)d_in[39];
    const float* a5    = (const float*)d_in[40];
    const float* W5    = (const float*)d_in[41];
    const float* b5    = (const float*)d_in[42];
    const int*   labels = (const int*)d_in[43];
    const int*   esrc   = (const int*)d_in[44];

    float* ws  = (float*)d_ws;
    float* bh  = ws;                          // [N,142]
    float* bq  = bh  + (size_t)N_NODES * F_IN;// [N,128] t, then q
    float* bk  = bq  + (size_t)N_NODES * HD;
    float* bv  = bk  + (size_t)N_NODES * HD;
    float* bs  = bv  + (size_t)N_NODES * HD;
    float* bag = bs  + (size_t)N_NODES * HD;  // agg; head doubles as E[3*128] pre-kD
    float* bh2 = bag + (size_t)N_NODES * HD;
    float* bE  = bag;                          // E[3][128] lives here until first kD
    float* out = (float*)d_out;

    dim3 gTile(N_NODES / 32);
    dim3 gTile4(N_NODES / 32, 4);
    dim3 gN(N_NODES);

    kE0<<<dim3(3), HD, 0, stream>>>(lemb, W2, b1, b2, bE);
    kA_t<F_IN><<<gTile, 256, 0, stream>>>(feat, labels, bE, W1, bn0g, bn0b, a3, bq);
    kB_t<<<dim3(N_NODES / 16), 192, 0, stream>>>(bq, feat, W3, b3, bh);

    // conv layer 0 (fin = 142)
    kC_t<F_IN><<<gTile4, 256, 0, stream>>>(bh,
        (const float*)d_in[11], (const float*)d_in[13], (const float*)d_in[15], (const float*)d_in[17],
        (const float*)d_in[12], (const float*)d_in[14], (const float*)d_in[16], (const float*)d_in[18],
        bq, bk, bv, bs);
    kD<<<gN, HD, 0, stream>>>(bq, bk, bv, esrc, bag);
    kE<<<gN, HD, 0, stream>>>(bs, bag, (const float*)d_in[19], (const float*)d_in[20],
                              (const float*)d_in[21], (const float*)d_in[22], aconv, bh2);

    // conv layer 1 (fin = 128)
    kC_t<HD><<<gTile4, 256, 0, stream>>>(bh2,
        (const float*)d_in[23], (const float*)d_in[25], (const float*)d_in[27], (const float*)d_in[29],
        (const float*)d_in[24], (const float*)d_in[26], (const float*)d_in[28], (const float*)d_in[30],
        bq, bk, bv, bs);
    kD<<<gN, HD, 0, stream>>>(bq, bk, bv, esrc, bag);
    kE<<<gN, HD, 0, stream>>>(bs, bag, (const float*)d_in[31], (const float*)d_in[32],
                              (const float*)d_in[33], (const float*)d_in[34], aconv, bh2);

    kF_t<<<gTile, 256, 0, stream>>>(bh2, W4, b4, bn1g, bn1b, a5, W5, b5, out);
}

// Round 3
// 410.418 us; speedup vs baseline: 2.0898x; 1.2287x over previous
//
#include <hip/hip_runtime.h>
#include <math.h>

#define N_NODES 20000
#define DEG 32
#define F_IN 142
#define HD 128
#define NHEAD 4
#define DHEAD 32
#define N_CLS 2

#define BN_SCALE 0.9999950000374997f
#define INV_SQRT_D 0.17677669529663687f

// ---- bf16 helpers (manual, RNE) ----
__device__ __forceinline__ unsigned short f2bf(float f) {
    unsigned u = __float_as_uint(f);
    unsigned r = (u + 0x7fffu + ((u >> 16) & 1u)) >> 16;
    return (unsigned short)r;
}
__device__ __forceinline__ float bf2f(unsigned short s) {
    return __uint_as_float((unsigned)s << 16);
}
__device__ __forceinline__ float bflo(unsigned u) { return __uint_as_float(u << 16); }
__device__ __forceinline__ float bfhi(unsigned u) { return __uint_as_float(u & 0xffff0000u); }

// ---------------- tiny precompute: E[l] = lemb[l] @ W2 + b1 + b2 (l=0..2) ----------------
__global__ void kE0(const float* __restrict__ lemb, const float* __restrict__ W2,
                    const float* __restrict__ b1, const float* __restrict__ b2,
                    float* __restrict__ E) {
    __shared__ float sl[F_IN];
    int l = blockIdx.x, c = threadIdx.x;
    for (int f = c; f < F_IN; f += HD) sl[f] = lemb[l * F_IN + f];
    __syncthreads();
    float acc = b1[c] + b2[c];
    for (int f = 0; f < F_IN; ++f) acc += sl[f] * W2[f * HD + c];
    E[l * HD + c] = acc;
}

// ---------------- shared tiled-GEMM core: 32 rows x 128 cols ----------------
template<int K>
__device__ __forceinline__ void gemm_acc(const float* __restrict__ W,
                                         const float* sA, float* sW,
                                         float acc[4][4], int tid, int tr, int tc) {
    int k0 = 0;
    for (; k0 + 16 <= K; k0 += 16) {
        __syncthreads();
        #pragma unroll
        for (int i = 0; i < 8; ++i)
            sW[tid + i * 256] = W[k0 * HD + tid + i * 256];
        __syncthreads();
        #pragma unroll
        for (int kk = 0; kk < 16; ++kk) {
            const float4 wv = *(const float4*)(sW + kk * HD + tc * 4);
            #pragma unroll
            for (int i = 0; i < 4; ++i) {
                const float av = sA[(tr * 4 + i) * K + k0 + kk];
                acc[i][0] = fmaf(av, wv.x, acc[i][0]);
                acc[i][1] = fmaf(av, wv.y, acc[i][1]);
                acc[i][2] = fmaf(av, wv.z, acc[i][2]);
                acc[i][3] = fmaf(av, wv.w, acc[i][3]);
            }
        }
    }
    if (k0 < K) {
        const int kb = K - k0;
        __syncthreads();
        for (int i = tid; i < kb * HD; i += 256)
            sW[i] = W[k0 * HD + i];
        __syncthreads();
        for (int kk = 0; kk < kb; ++kk) {
            const float4 wv = *(const float4*)(sW + kk * HD + tc * 4);
            #pragma unroll
            for (int i = 0; i < 4; ++i) {
                const float av = sA[(tr * 4 + i) * K + k0 + kk];
                acc[i][0] = fmaf(av, wv.x, acc[i][0]);
                acc[i][1] = fmaf(av, wv.y, acc[i][1]);
                acc[i][2] = fmaf(av, wv.z, acc[i][2]);
                acc[i][3] = fmaf(av, wv.w, acc[i][3]);
            }
        }
    }
}

// ---------------- kA: t = PReLU(BN(feat@W1 + E[label])) ----------------
template<int K>
__global__ __launch_bounds__(256) void kA_t(const float* __restrict__ A,
        const int* __restrict__ labels, const float* __restrict__ E,
        const float* __restrict__ W1,
        const float* __restrict__ bng, const float* __restrict__ bnb,
        const float* __restrict__ a3, float* __restrict__ tOut) {
    __shared__ float sA[32 * K];
    __shared__ float sW[16 * HD];
    __shared__ int sLab[32];
    const int tid = threadIdx.x, tr = tid >> 5, tc = tid & 31;
    const int row0 = blockIdx.x * 32;
    for (int i = tid; i < 32 * K; i += 256) sA[i] = A[(size_t)row0 * K + i];
    if (tid < 32) sLab[tid] = labels[row0 + tid];
    float acc[4][4] = {};
    gemm_acc<K>(W1, sA, sW, acc, tid, tr, tc);
    const int c = tc * 4;
    const float4 g4 = *(const float4*)(bng + c);
    const float4 bb4 = *(const float4*)(bnb + c);
    const float al = a3[0];
    #pragma unroll
    for (int i = 0; i < 4; ++i) {
        const int r = tr * 4 + i;
        const float4 e4 = *(const float4*)(E + sLab[r] * HD + c);
        float4 o;
        o.x = (acc[i][0] + e4.x) * BN_SCALE * g4.x + bb4.x;
        o.y = (acc[i][1] + e4.y) * BN_SCALE * g4.y + bb4.y;
        o.z = (acc[i][2] + e4.z) * BN_SCALE * g4.z + bb4.z;
        o.w = (acc[i][3] + e4.w) * BN_SCALE * g4.w + bb4.w;
        o.x = (o.x >= 0.f) ? o.x : al * o.x;
        o.y = (o.y >= 0.f) ? o.y : al * o.y;
        o.z = (o.z >= 0.f) ? o.z : al * o.z;
        o.w = (o.w >= 0.f) ? o.w : al * o.w;
        *(float4*)(tOut + (size_t)(row0 + r) * HD + c) = o;
    }
}

// ---------------- kB: h = feat + t @ W3 + b3 ----------------
__global__ __launch_bounds__(192) void kB_t(const float* __restrict__ t,
        const float* __restrict__ feat, const float* __restrict__ W3,
        const float* __restrict__ b3, float* __restrict__ h) {
    __shared__ float sA[16 * HD];
    const int tid = threadIdx.x;
    const int row0 = blockIdx.x * 16;
    for (int i = tid; i < 16 * HD; i += 192) sA[i] = t[(size_t)row0 * HD + i];
    __syncthreads();
    const int c = (tid < F_IN) ? tid : (F_IN - 1);
    float acc[16] = {};
    for (int k0 = 0; k0 < HD; k0 += 8) {
        float w[8];
        #pragma unroll
        for (int kk = 0; kk < 8; ++kk) w[kk] = W3[(k0 + kk) * F_IN + c];
        #pragma unroll
        for (int r = 0; r < 16; ++r) {
            const float4 a0 = *(const float4*)(sA + r * HD + k0);
            const float4 a1 = *(const float4*)(sA + r * HD + k0 + 4);
            acc[r] = fmaf(a0.x, w[0], acc[r]);
            acc[r] = fmaf(a0.y, w[1], acc[r]);
            acc[r] = fmaf(a0.z, w[2], acc[r]);
            acc[r] = fmaf(a0.w, w[3], acc[r]);
            acc[r] = fmaf(a1.x, w[4], acc[r]);
            acc[r] = fmaf(a1.y, w[5], acc[r]);
            acc[r] = fmaf(a1.z, w[6], acc[r]);
            acc[r] = fmaf(a1.w, w[7], acc[r]);
        }
    }
    if (tid < F_IN) {
        const float bb = b3[c];
        #pragma unroll
        for (int r = 0; r < 16; ++r)
            h[(size_t)(row0 + r) * F_IN + c] =
                feat[(size_t)(row0 + r) * F_IN + c] + acc[r] + bb;
    }
}

// ---------------- kC: fused projections; q/k/v -> bf16 head-major, skip -> fp32 ----------------
template<int K>
__global__ __launch_bounds__(256) void kC_t(const float* __restrict__ A,
        const float* __restrict__ Wq, const float* __restrict__ Wk,
        const float* __restrict__ Wv, const float* __restrict__ Ws,
        const float* __restrict__ bq, const float* __restrict__ bk,
        const float* __restrict__ bv, const float* __restrict__ bs,
        unsigned short* __restrict__ qh, unsigned short* __restrict__ kh,
        unsigned short* __restrict__ vh, float* __restrict__ s) {
    __shared__ float sA[32 * K];
    __shared__ float sW[16 * HD];
    const float* Wt[4] = {Wq, Wk, Wv, Ws};
    const float* bt[4] = {bq, bk, bv, bs};
    unsigned short* ht[3] = {qh, kh, vh};
    const int m = blockIdx.y;
    const float* W = Wt[m];
    const float* bias = bt[m];
    const int tid = threadIdx.x, tr = tid >> 5, tc = tid & 31;
    const int row0 = blockIdx.x * 32;
    for (int i = tid; i < 32 * K; i += 256) sA[i] = A[(size_t)row0 * K + i];
    float acc[4][4] = {};
    gemm_acc<K>(W, sA, sW, acc, tid, tr, tc);
    const int c = tc * 4;
    const float4 b4v = *(const float4*)(bias + c);
    if (m < 3) {
        unsigned short* outh = ht[m];
        const int hc = tc >> 3;          // head = c/32
        const int d0 = (tc & 7) * 4;     // dim within head
        #pragma unroll
        for (int i = 0; i < 4; ++i) {
            const int r = row0 + tr * 4 + i;
            ushort4 o;
            o.x = f2bf(acc[i][0] + b4v.x);
            o.y = f2bf(acc[i][1] + b4v.y);
            o.z = f2bf(acc[i][2] + b4v.z);
            o.w = f2bf(acc[i][3] + b4v.w);
            *(ushort4*)(outh + ((size_t)hc * N_NODES + r) * DHEAD + d0) = o;
        }
    } else {
        #pragma unroll
        for (int i = 0; i < 4; ++i) {
            const int r = row0 + tr * 4 + i;
            float4 o;
            o.x = acc[i][0] + b4v.x;
            o.y = acc[i][1] + b4v.y;
            o.z = acc[i][2] + b4v.z;
            o.w = acc[i][3] + b4v.w;
            *(float4*)(s + (size_t)r * HD + c) = o;
        }
    }
}

// ---------------- kD: head-split attention, bf16 gathers, 8 nodes/block ----------------
__global__ __launch_bounds__(256) void kD_h(const unsigned short* __restrict__ qh,
        const unsigned short* __restrict__ kh, const unsigned short* __restrict__ vh,
        const int* __restrict__ esrc, float* __restrict__ agg) {
    __shared__ float sk[8][DHEAD];
    __shared__ int ssrc[8][DEG];
    __shared__ float sa[8][DEG];
    const int h = blockIdx.y;
    const int n0 = blockIdx.x * 8;
    const int t = threadIdx.x;
    const int j = t >> 5, e = t & 31;

    ssrc[j][e] = esrc[n0 * DEG + t];
    if (t < 128) {
        unsigned u = *((const unsigned*)(kh + ((size_t)h * N_NODES + n0) * DHEAD) + t);
        float* skf = &sk[0][0];
        skf[2 * t]     = bflo(u);
        skf[2 * t + 1] = bfhi(u);
    }
    __syncthreads();

    // scores
    const int src = ssrc[j][e];
    const uint4* qp = (const uint4*)(qh + ((size_t)h * N_NODES + src) * DHEAD);
    const float* kj = sk[j];
    float sc = 0.f;
    #pragma unroll
    for (int i = 0; i < 4; ++i) {
        uint4 u = qp[i];
        sc = fmaf(bflo(u.x), kj[i * 8 + 0], sc);
        sc = fmaf(bfhi(u.x), kj[i * 8 + 1], sc);
        sc = fmaf(bflo(u.y), kj[i * 8 + 2], sc);
        sc = fmaf(bfhi(u.y), kj[i * 8 + 3], sc);
        sc = fmaf(bflo(u.z), kj[i * 8 + 4], sc);
        sc = fmaf(bfhi(u.z), kj[i * 8 + 5], sc);
        sc = fmaf(bflo(u.w), kj[i * 8 + 6], sc);
        sc = fmaf(bfhi(u.w), kj[i * 8 + 7], sc);
    }
    sc *= INV_SQRT_D;
    float m = sc;
    #pragma unroll
    for (int off = 16; off > 0; off >>= 1)
        m = fmaxf(m, __shfl_xor(m, off, 32));
    float p = expf(sc - m);
    float ssum = p;
    #pragma unroll
    for (int off = 16; off > 0; off >>= 1)
        ssum += __shfl_xor(ssum, off, 32);
    sa[j][e] = p / ssum;
    __syncthreads();

    // aggregation: thread -> (node j, dim d)
    const int d = t & 31;
    const unsigned short* vbase = vh + (size_t)h * N_NODES * DHEAD + d;
    float acc = 0.f;
    #pragma unroll
    for (int e2 = 0; e2 < DEG; ++e2) {
        const int s2 = ssrc[j][e2];
        acc = fmaf(bf2f(vbase[(size_t)s2 * DHEAD]), sa[j][e2], acc);
    }
    agg[(size_t)(n0 + j) * HD + h * DHEAD + d] = acc;
}

// ---------------- fast 128-thread block reduce (2 waves) ----------------
__device__ __forceinline__ float blockSum128(float v, float* s2, int tid) {
    #pragma unroll
    for (int o = 32; o > 0; o >>= 1) v += __shfl_xor(v, o, 64);
    if ((tid & 63) == 0) s2[tid >> 6] = v;
    __syncthreads();
    float r = s2[0] + s2[1];
    __syncthreads();
    return r;
}

// ---------------- kE: scalar gate + gated mix + LayerNorm + PReLU ----------------
__global__ void kE(const float* __restrict__ skip, const float* __restrict__ agg,
                   const float* __restrict__ Wg, const float* __restrict__ bg,
                   const float* __restrict__ lng, const float* __restrict__ lnb,
                   const float* __restrict__ ac,
                   float* __restrict__ hout) {
    __shared__ float red[2];
    int n = blockIdx.x, c = threadIdx.x;
    float sk = skip[n * HD + c], ag = agg[n * HD + c];
    float part = sk * Wg[c] + ag * Wg[HD + c] + (sk - ag) * Wg[2 * HD + c];
    float z = blockSum128(part, red, c) + bg[0];
    float g = 1.f / (1.f + expf(-z));
    float r = g * sk + (1.f - g) * ag;
    float mean = blockSum128(r, red, c) * (1.f / HD);
    float dv = r - mean;
    float var = blockSum128(dv * dv, red, c) * (1.f / HD);
    float y = dv * rsqrtf(var + 1e-5f) * lng[c] + lnb[c];
    float a = ac[0];
    hout[n * HD + c] = (y >= 0.f) ? y : a * y;
}

// ---------------- kF: out = PReLU(BN(h@W4 + b4)) @ W5 + b5, tiled ----------------
__global__ __launch_bounds__(256) void kF_t(const float* __restrict__ A,
        const float* __restrict__ W4, const float* __restrict__ b4,
        const float* __restrict__ bng, const float* __restrict__ bnb,
        const float* __restrict__ a5, const float* __restrict__ W5,
        const float* __restrict__ b5, float* __restrict__ out) {
    __shared__ float sA[32 * HD];
    __shared__ float sW[16 * HD];
    const int tid = threadIdx.x, tr = tid >> 5, tc = tid & 31;
    const int row0 = blockIdx.x * 32;
    for (int i = tid; i < 32 * HD; i += 256) sA[i] = A[(size_t)row0 * HD + i];
    float acc[4][4] = {};
    gemm_acc<HD>(W4, sA, sW, acc, tid, tr, tc);
    const int c = tc * 4;
    const float4 bb = *(const float4*)(b4 + c);
    const float4 g4 = *(const float4*)(bng + c);
    const float4 bn4 = *(const float4*)(bnb + c);
    const float al = a5[0];
    const float4 w5a = *(const float4*)(W5 + c * 2);
    const float4 w5b = *(const float4*)(W5 + c * 2 + 4);
    const float b50 = b5[0], b51 = b5[1];
    #pragma unroll
    for (int i = 0; i < 4; ++i) {
        float y0 = (acc[i][0] + bb.x) * BN_SCALE * g4.x + bn4.x;
        float y1 = (acc[i][1] + bb.y) * BN_SCALE * g4.y + bn4.y;
        float y2 = (acc[i][2] + bb.z) * BN_SCALE * g4.z + bn4.z;
        float y3 = (acc[i][3] + bb.w) * BN_SCALE * g4.w + bn4.w;
        y0 = (y0 >= 0.f) ? y0 : al * y0;
        y1 = (y1 >= 0.f) ? y1 : al * y1;
        y2 = (y2 >= 0.f) ? y2 : al * y2;
        y3 = (y3 >= 0.f) ? y3 : al * y3;
        float p0 = y0 * w5a.x + y1 * w5a.z + y2 * w5b.x + y3 * w5b.z;
        float p1 = y0 * w5a.y + y1 * w5a.w + y2 * w5b.y + y3 * w5b.w;
        #pragma unroll
        for (int off = 16; off > 0; off >>= 1) {
            p0 += __shfl_xor(p0, off, 32);
            p1 += __shfl_xor(p1, off, 32);
        }
        if (tc == 0) {
            const int r = row0 + tr * 4 + i;
            out[r * N_CLS + 0] = p0 + b50;
            out[r * N_CLS + 1] = p1 + b51;
        }
    }
}

extern "C" void kernel_launch(void* const* d_in, const int* in_sizes, int n_in,
                              void* d_out, int out_size, void* d_ws, size_t ws_size,
                              hipStream_t stream) {
    const float* feat  = (const float*)d_in[0];
    const float* lemb  = (const float*)d_in[1];
    const float* W1    = (const float*)d_in[2];
    const float* b1    = (const float*)d_in[3];
    const float* W2    = (const float*)d_in[4];
    const float* b2    = (const float*)d_in[5];
    const float* bn0g  = (const float*)d_in[6];
    const float* bn0b  = (const float*)d_in[7];
    const float* a3    = (const float*)d_in[8];
    const float* W3    = (const float*)d_in[9];
    const float* b3    = (const float*)d_in[10];
    const float* aconv = (const float*)d_in[35];
    const float* W4    = (const float*)d_in[36];
    const float* b4    = (const float*)d_in[37];
    const float* bn1g  = (const float*)d_in[38];
    const float* bn1b  = (const float*)d_in[39];
    const float* a5    = (const float*)d_in[40];
    const float* W5    = (const float*)d_in[41];
    const float* b5    = (const float*)d_in[42];
    const int*   labels = (const int*)d_in[43];
    const int*   esrc   = (const int*)d_in[44];

    char* ws = (char*)d_ws;
    float* bh  = (float*)ws;                                   ws += sizeof(float) * N_NODES * F_IN;
    float* bt  = (float*)ws;                                   ws += sizeof(float) * N_NODES * HD;
    float* bs  = (float*)ws;                                   ws += sizeof(float) * N_NODES * HD;
    float* bag = (float*)ws;                                   ws += sizeof(float) * N_NODES * HD;
    float* bh2 = (float*)ws;                                   ws += sizeof(float) * N_NODES * HD;
    unsigned short* bqh = (unsigned short*)ws;                 ws += sizeof(short) * N_NODES * HD;
    unsigned short* bkh = (unsigned short*)ws;                 ws += sizeof(short) * N_NODES * HD;
    unsigned short* bvh = (unsigned short*)ws;                 ws += sizeof(short) * N_NODES * HD;
    float* bE = bag;    // E[3][128] lives in bag until first kD
    float* out = (float*)d_out;

    dim3 gTile(N_NODES / 32);
    dim3 gTile4(N_NODES / 32, 4);
    dim3 gD(N_NODES / 8, NHEAD);
    dim3 gN(N_NODES);

    kE0<<<dim3(3), HD, 0, stream>>>(lemb, W2, b1, b2, bE);
    kA_t<F_IN><<<gTile, 256, 0, stream>>>(feat, labels, bE, W1, bn0g, bn0b, a3, bt);
    kB_t<<<dim3(N_NODES / 16), 192, 0, stream>>>(bt, feat, W3, b3, bh);

    // conv layer 0 (fin = 142)
    kC_t<F_IN><<<gTile4, 256, 0, stream>>>(bh,
        (const float*)d_in[11], (const float*)d_in[13], (const float*)d_in[15], (const float*)d_in[17],
        (const float*)d_in[12], (const float*)d_in[14], (const float*)d_in[16], (const float*)d_in[18],
        bqh, bkh, bvh, bs);
    kD_h<<<gD, 256, 0, stream>>>(bqh, bkh, bvh, esrc, bag);
    kE<<<gN, HD, 0, stream>>>(bs, bag, (const float*)d_in[19], (const float*)d_in[20],
                              (const float*)d_in[21], (const float*)d_in[22], aconv, bh2);

    // conv layer 1 (fin = 128)
    kC_t<HD><<<gTile4, 256, 0, stream>>>(bh2,
        (const float*)d_in[23], (const float*)d_in[25], (const float*)d_in[27], (const float*)d_in[29],
        (const float*)d_in[24], (const float*)d_in[26], (const float*)d_in[28], (const float*)d_in[30],
        bqh, bkh, bvh, bs);
    kD_h<<<gD, 256, 0, stream>>>(bqh, bkh, bvh, esrc, bag);
    kE<<<gN, HD, 0, stream>>>(bs, bag, (const float*)d_in[31], (const float*)d_in[32],
                              (const float*)d_in[33], (const float*)d_in[34], aconv, bh2);

    kF_t<<<gTile, 256, 0, stream>>>(bh2, W4, b4, bn1g, bn1b, a5, W5, b5, out);
}

// Round 6
// 371.551 us; speedup vs baseline: 2.3084x; 1.1046x over previous
//
#include <hip/hip_runtime.h>
#include <math.h>

#define N_NODES 20000
#define DEG 32
#define F_IN 142
#define HD 128
#define NHEAD 4
#define DHEAD 32
#define N_CLS 2

#define BN_SCALE 0.9999950000374997f
#define INV_SQRT_D 0.17677669529663687f

typedef short v8s __attribute__((ext_vector_type(8)));
typedef float v4f __attribute__((ext_vector_type(4)));

// ---- bf16 helpers (manual, RNE) ----
__device__ __forceinline__ unsigned short f2bf(float f) {
    unsigned u = __float_as_uint(f);
    return (unsigned short)((u + 0x7fffu + ((u >> 16) & 1u)) >> 16);
}
__device__ __forceinline__ unsigned pack2bf(float a, float b) {
    return (unsigned)f2bf(a) | ((unsigned)f2bf(b) << 16);
}
__device__ __forceinline__ float bf2f(unsigned short s) {
    return __uint_as_float((unsigned)s << 16);
}
__device__ __forceinline__ float bflo(unsigned u) { return __uint_as_float(u << 16); }
__device__ __forceinline__ float bfhi(unsigned u) { return __uint_as_float(u & 0xffff0000u); }

__device__ __forceinline__ v8s pack8(float4 f0, float4 f1) {
    union { v8s s; unsigned u[4]; } x;
    x.u[0] = pack2bf(f0.x, f0.y);
    x.u[1] = pack2bf(f0.z, f0.w);
    x.u[2] = pack2bf(f1.x, f1.y);
    x.u[3] = pack2bf(f1.z, f1.w);
    return x.s;
}

// ---------------- kE0: E[l] = lemb[l] @ W2 + b1 + b2 (l=0..2)  [R2-proven] ----------------
__global__ void kE0(const float* __restrict__ lemb, const float* __restrict__ W2,
                    const float* __restrict__ b1, const float* __restrict__ b2,
                    float* __restrict__ E) {
    __shared__ float sl[F_IN];
    int l = blockIdx.x, c = threadIdx.x;
    for (int f = c; f < F_IN; f += HD) sl[f] = lemb[l * F_IN + f];
    __syncthreads();
    float acc = b1[c] + b2[c];
    for (int f = 0; f < F_IN; ++f) acc += sl[f] * W2[f * HD + c];
    E[l * HD + c] = acc;
}

// ---------------- kSwiz4: fp32 W[K][128] -> bf16 B-fragment layout ----------------
// Tile (nt,kc): lane L holds W[kc*32+(L>>4)*8+j][nt*16+(L&15)], j=0..7 contiguous.
template<int KC, int K>
__global__ void kSwiz4(const float* Wa, const float* Wb, const float* Wc,
                       const float* Wd, short* __restrict__ out) {
    const float* Wt[4] = {Wa, Wb, Wc, Wd};
    const float* W = Wt[blockIdx.y];
    const int tile = blockIdx.x;        // nt*KC + kc; grid.x = 8*KC
    const int kc = tile % KC, nt = tile / KC;
    const int L = threadIdx.x;
    const int n = nt * 16 + (L & 15);
    const int kb = kc * 32 + (L >> 4) * 8;
    short v[8] __attribute__((aligned(16)));
    #pragma unroll
    for (int j = 0; j < 8; ++j) {
        int k = kb + j;
        v[j] = (k < K) ? (short)f2bf(W[(size_t)k * HD + n]) : (short)0;
    }
    short* dst = out + (size_t)blockIdx.y * (8 * KC * 64 * 8) + ((size_t)tile * 64 + L) * 8;
    *(uint4*)dst = *(const uint4*)v;
}

// ---------------- fp32 tiled-GEMM core [R2-proven] ----------------
template<int K>
__device__ __forceinline__ void gemm_acc(const float* __restrict__ W,
                                         const float* sA, float* sW,
                                         float acc[4][4], int tid, int tr, int tc) {
    int k0 = 0;
    for (; k0 + 16 <= K; k0 += 16) {
        __syncthreads();
        #pragma unroll
        for (int i = 0; i < 8; ++i)
            sW[tid + i * 256] = W[k0 * HD + tid + i * 256];
        __syncthreads();
        #pragma unroll
        for (int kk = 0; kk < 16; ++kk) {
            const float4 wv = *(const float4*)(sW + kk * HD + tc * 4);
            #pragma unroll
            for (int i = 0; i < 4; ++i) {
                const float av = sA[(tr * 4 + i) * K + k0 + kk];
                acc[i][0] = fmaf(av, wv.x, acc[i][0]);
                acc[i][1] = fmaf(av, wv.y, acc[i][1]);
                acc[i][2] = fmaf(av, wv.z, acc[i][2]);
                acc[i][3] = fmaf(av, wv.w, acc[i][3]);
            }
        }
    }
    if (k0 < K) {
        const int kb = K - k0;
        __syncthreads();
        for (int i = tid; i < kb * HD; i += 256)
            sW[i] = W[k0 * HD + i];
        __syncthreads();
        for (int kk = 0; kk < kb; ++kk) {
            const float4 wv = *(const float4*)(sW + kk * HD + tc * 4);
            #pragma unroll
            for (int i = 0; i < 4; ++i) {
                const float av = sA[(tr * 4 + i) * K + k0 + kk];
                acc[i][0] = fmaf(av, wv.x, acc[i][0]);
                acc[i][1] = fmaf(av, wv.y, acc[i][1]);
                acc[i][2] = fmaf(av, wv.z, acc[i][2]);
                acc[i][3] = fmaf(av, wv.w, acc[i][3]);
            }
        }
    }
}

// ---------------- kA: t = PReLU(BN(feat@W1 + E[label])), fp32 [R2-proven] ----------------
template<int K>
__global__ __launch_bounds__(256) void kA_t(const float* __restrict__ A,
        const int* __restrict__ labels, const float* __restrict__ E,
        const float* __restrict__ W1,
        const float* __restrict__ bng, const float* __restrict__ bnb,
        const float* __restrict__ a3, float* __restrict__ tOut) {
    __shared__ float sA[32 * K];
    __shared__ float sW[16 * HD];
    __shared__ int sLab[32];
    const int tid = threadIdx.x, tr = tid >> 5, tc = tid & 31;
    const int row0 = blockIdx.x * 32;
    for (int i = tid; i < 32 * K; i += 256) sA[i] = A[(size_t)row0 * K + i];
    if (tid < 32) sLab[tid] = labels[row0 + tid];
    float acc[4][4] = {};
    gemm_acc<K>(W1, sA, sW, acc, tid, tr, tc);
    const int c = tc * 4;
    const float4 g4 = *(const float4*)(bng + c);
    const float4 bb4 = *(const float4*)(bnb + c);
    const float al = a3[0];
    #pragma unroll
    for (int i = 0; i < 4; ++i) {
        const int r = tr * 4 + i;
        const float4 e4 = *(const float4*)(E + sLab[r] * HD + c);
        float4 o;
        o.x = (acc[i][0] + e4.x) * BN_SCALE * g4.x + bb4.x;
        o.y = (acc[i][1] + e4.y) * BN_SCALE * g4.y + bb4.y;
        o.z = (acc[i][2] + e4.z) * BN_SCALE * g4.z + bb4.z;
        o.w = (acc[i][3] + e4.w) * BN_SCALE * g4.w + bb4.w;
        o.x = (o.x >= 0.f) ? o.x : al * o.x;
        o.y = (o.y >= 0.f) ? o.y : al * o.y;
        o.z = (o.z >= 0.f) ? o.z : al * o.z;
        o.w = (o.w >= 0.f) ? o.w : al * o.w;
        *(float4*)(tOut + (size_t)(row0 + r) * HD + c) = o;
    }
}

// ---------------- kB: h = feat + t @ W3 + b3, fp32 [R2-proven] ----------------
__global__ __launch_bounds__(192) void kB_t(const float* __restrict__ t,
        const float* __restrict__ feat, const float* __restrict__ W3,
        const float* __restrict__ b3, float* __restrict__ h) {
    __shared__ float sA[16 * HD];
    const int tid = threadIdx.x;
    const int row0 = blockIdx.x * 16;
    for (int i = tid; i < 16 * HD; i += 192) sA[i] = t[(size_t)row0 * HD + i];
    __syncthreads();
    const int c = (tid < F_IN) ? tid : (F_IN - 1);
    float acc[16] = {};
    for (int k0 = 0; k0 < HD; k0 += 8) {
        float w[8];
        #pragma unroll
        for (int kk = 0; kk < 8; ++kk) w[kk] = W3[(k0 + kk) * F_IN + c];
        #pragma unroll
        for (int r = 0; r < 16; ++r) {
            const float4 a0 = *(const float4*)(sA + r * HD + k0);
            const float4 a1 = *(const float4*)(sA + r * HD + k0 + 4);
            acc[r] = fmaf(a0.x, w[0], acc[r]);
            acc[r] = fmaf(a0.y, w[1], acc[r]);
            acc[r] = fmaf(a0.z, w[2], acc[r]);
            acc[r] = fmaf(a0.w, w[3], acc[r]);
            acc[r] = fmaf(a1.x, w[4], acc[r]);
            acc[r] = fmaf(a1.y, w[5], acc[r]);
            acc[r] = fmaf(a1.z, w[6], acc[r]);
            acc[r] = fmaf(a1.w, w[7], acc[r]);
        }
    }
    if (tid < F_IN) {
        const float bb = b3[c];
        #pragma unroll
        for (int r = 0; r < 16; ++r)
            h[(size_t)(row0 + r) * F_IN + c] =
                feat[(size_t)(row0 + r) * F_IN + c] + acc[r] + bb;
    }
}

// ---------------- kC (NEW, minimal MFMA): fp32 LDS staging, in-register bf16 pack ----------------
// K: input width; LDSK: padded LDS row (floats, 16B-mult); KC: k-chunks of 32.
template<int K, int LDSK, int KC>
__global__ __launch_bounds__(256) void kC_mf(const float* __restrict__ A,
        const short* __restrict__ WfBase,
        const float* __restrict__ bq, const float* __restrict__ bk,
        const float* __restrict__ bv, const float* __restrict__ bs,
        unsigned short* __restrict__ qh, unsigned short* __restrict__ kh,
        unsigned short* __restrict__ vh, float* __restrict__ sOut) {
    __shared__ float4 sAv[32 * LDSK / 4];
    float* sA = (float*)sAv;
    const int tid = threadIdx.x;
    const int row0 = blockIdx.x * 32;
    const int mat = blockIdx.y;
    // stage A (scalar fp32, R2 pattern)
    for (int idx = tid; idx < 32 * K; idx += 256) {
        int r = idx / K, c = idx - r * K;
        sA[r * LDSK + c] = A[(size_t)(row0 + r) * K + c];
    }
    if (K < KC * 32) {   // zero-fill k in [K, KC*32)
        const int ZC = KC * 32 - K;
        for (int idx = tid; idx < 32 * ZC; idx += 256) {
            int r = idx / ZC, c = idx - r * ZC;
            sA[r * LDSK + K + c] = 0.f;
        }
    }
    __syncthreads();

    const short* Wf = WfBase + (size_t)mat * (KC * 4096);
    const float* bias = (mat == 0) ? bq : (mat == 1) ? bk : (mat == 2) ? bv : bs;
    const int lane = tid & 63, w = tid >> 6;
    const int m = lane & 15, q = lane >> 4;
    const int nt0 = w * 2, nt1 = nt0 + 1;
    v4f acc00 = {0.f,0.f,0.f,0.f}, acc01 = acc00, acc10 = acc00, acc11 = acc00;
    #pragma unroll
    for (int kc = 0; kc < KC; ++kc) {
        const float* r0 = sA + m * LDSK + kc * 32 + q * 8;
        const float* r1 = sA + (16 + m) * LDSK + kc * 32 + q * 8;
        v8s a0 = pack8(*(const float4*)r0, *(const float4*)(r0 + 4));
        v8s a1 = pack8(*(const float4*)r1, *(const float4*)(r1 + 4));
        v8s b0 = *(const v8s*)(Wf + ((size_t)((nt0 * KC + kc) * 64 + lane)) * 8);
        v8s b1 = *(const v8s*)(Wf + ((size_t)((nt1 * KC + kc) * 64 + lane)) * 8);
        acc00 = __builtin_amdgcn_mfma_f32_16x16x32_bf16(a0, b0, acc00, 0, 0, 0);
        acc01 = __builtin_amdgcn_mfma_f32_16x16x32_bf16(a0, b1, acc01, 0, 0, 0);
        acc10 = __builtin_amdgcn_mfma_f32_16x16x32_bf16(a1, b0, acc10, 0, 0, 0);
        acc11 = __builtin_amdgcn_mfma_f32_16x16x32_bf16(a1, b1, acc11, 0, 0, 0);
    }
    const int c0 = w * 32 + m, c1 = c0 + 16;
    const float b0v = bias[c0], b1v = bias[c1];
    if (mat < 3) {
        // head-major [H][N][32]; wave w == head w; within-head dims m and m+16
        unsigned short* outh = (mat == 0) ? qh : (mat == 1) ? kh : vh;
        unsigned short* outw = outh + ((size_t)w * N_NODES + row0) * DHEAD;
        #pragma unroll
        for (int rt = 0; rt < 2; ++rt) {
            v4f A0 = rt ? acc10 : acc00;
            v4f A1 = rt ? acc11 : acc01;
            #pragma unroll
            for (int i = 0; i < 4; ++i) {
                const int r = rt * 16 + q * 4 + i;
                outw[(size_t)r * DHEAD + m]      = f2bf(A0[i] + b0v);
                outw[(size_t)r * DHEAD + 16 + m] = f2bf(A1[i] + b1v);
            }
        }
    } else {
        #pragma unroll
        for (int rt = 0; rt < 2; ++rt) {
            v4f A0 = rt ? acc10 : acc00;
            v4f A1 = rt ? acc11 : acc01;
            #pragma unroll
            for (int i = 0; i < 4; ++i) {
                const int r = rt * 16 + q * 4 + i;
                sOut[(size_t)(row0 + r) * HD + c0] = A0[i] + b0v;
                sOut[(size_t)(row0 + r) * HD + c1] = A1[i] + b1v;
            }
        }
    }
}

// ---------------- kD: head-split attention, bf16 gathers [R2-proven] ----------------
__global__ __launch_bounds__(256) void kD_h(const unsigned short* __restrict__ qh,
        const unsigned short* __restrict__ kh, const unsigned short* __restrict__ vh,
        const int* __restrict__ esrc, float* __restrict__ agg) {
    __shared__ float sk[8][DHEAD];
    __shared__ int ssrc[8][DEG];
    __shared__ float sa[8][DEG];
    const int h = blockIdx.y;
    const int n0 = blockIdx.x * 8;
    const int t = threadIdx.x;
    const int j = t >> 5, e = t & 31;

    ssrc[j][e] = esrc[n0 * DEG + t];
    if (t < 128) {
        unsigned u = *((const unsigned*)(kh + ((size_t)h * N_NODES + n0) * DHEAD) + t);
        float* skf = &sk[0][0];
        skf[2 * t]     = bflo(u);
        skf[2 * t + 1] = bfhi(u);
    }
    __syncthreads();

    const int src = ssrc[j][e];
    const uint4* qp = (const uint4*)(qh + ((size_t)h * N_NODES + src) * DHEAD);
    const float* kj = sk[j];
    float sc = 0.f;
    #pragma unroll
    for (int i = 0; i < 4; ++i) {
        uint4 u = qp[i];
        sc = fmaf(bflo(u.x), kj[i * 8 + 0], sc);
        sc = fmaf(bfhi(u.x), kj[i * 8 + 1], sc);
        sc = fmaf(bflo(u.y), kj[i * 8 + 2], sc);
        sc = fmaf(bfhi(u.y), kj[i * 8 + 3], sc);
        sc = fmaf(bflo(u.z), kj[i * 8 + 4], sc);
        sc = fmaf(bfhi(u.z), kj[i * 8 + 5], sc);
        sc = fmaf(bflo(u.w), kj[i * 8 + 6], sc);
        sc = fmaf(bfhi(u.w), kj[i * 8 + 7], sc);
    }
    sc *= INV_SQRT_D;
    float m = sc;
    #pragma unroll
    for (int off = 16; off > 0; off >>= 1)
        m = fmaxf(m, __shfl_xor(m, off, 32));
    float p = expf(sc - m);
    float ssum = p;
    #pragma unroll
    for (int off = 16; off > 0; off >>= 1)
        ssum += __shfl_xor(ssum, off, 32);
    sa[j][e] = p / ssum;
    __syncthreads();

    const int d = t & 31;
    const unsigned short* vbase = vh + (size_t)h * N_NODES * DHEAD + d;
    float acc = 0.f;
    #pragma unroll
    for (int e2 = 0; e2 < DEG; ++e2) {
        const int s2 = ssrc[j][e2];
        acc = fmaf(bf2f(vbase[(size_t)s2 * DHEAD]), sa[j][e2], acc);
    }
    agg[(size_t)(n0 + j) * HD + h * DHEAD + d] = acc;
}

// ---------------- fast 128-thread block reduce [R2-proven] ----------------
__device__ __forceinline__ float blockSum128(float v, float* s2, int tid) {
    #pragma unroll
    for (int o = 32; o > 0; o >>= 1) v += __shfl_xor(v, o, 64);
    if ((tid & 63) == 0) s2[tid >> 6] = v;
    __syncthreads();
    float r = s2[0] + s2[1];
    __syncthreads();
    return r;
}

// ---------------- kE: gate + gated mix + LayerNorm + PReLU, fp32 [R2-proven] ----------------
__global__ void kE(const float* __restrict__ skip, const float* __restrict__ agg,
                   const float* __restrict__ Wg, const float* __restrict__ bg,
                   const float* __restrict__ lng, const float* __restrict__ lnb,
                   const float* __restrict__ ac,
                   float* __restrict__ hout) {
    __shared__ float red[2];
    int n = blockIdx.x, c = threadIdx.x;
    float sk = skip[n * HD + c], ag = agg[n * HD + c];
    float part = sk * Wg[c] + ag * Wg[HD + c] + (sk - ag) * Wg[2 * HD + c];
    float z = blockSum128(part, red, c) + bg[0];
    float g = 1.f / (1.f + expf(-z));
    float r = g * sk + (1.f - g) * ag;
    float mean = blockSum128(r, red, c) * (1.f / HD);
    float dv = r - mean;
    float var = blockSum128(dv * dv, red, c) * (1.f / HD);
    float y = dv * rsqrtf(var + 1e-5f) * lng[c] + lnb[c];
    float a = ac[0];
    hout[n * HD + c] = (y >= 0.f) ? y : a * y;
}

// ---------------- kF: out = PReLU(BN(h@W4 + b4)) @ W5 + b5, fp32 [R2-proven] ----------------
__global__ __launch_bounds__(256) void kF_t(const float* __restrict__ A,
        const float* __restrict__ W4, const float* __restrict__ b4,
        const float* __restrict__ bng, const float* __restrict__ bnb,
        const float* __restrict__ a5, const float* __restrict__ W5,
        const float* __restrict__ b5, float* __restrict__ out) {
    __shared__ float sA[32 * HD];
    __shared__ float sW[16 * HD];
    const int tid = threadIdx.x, tr = tid >> 5, tc = tid & 31;
    const int row0 = blockIdx.x * 32;
    for (int i = tid; i < 32 * HD; i += 256) sA[i] = A[(size_t)row0 * HD + i];
    float acc[4][4] = {};
    gemm_acc<HD>(W4, sA, sW, acc, tid, tr, tc);
    const int c = tc * 4;
    const float4 bb = *(const float4*)(b4 + c);
    const float4 g4 = *(const float4*)(bng + c);
    const float4 bn4 = *(const float4*)(bnb + c);
    const float al = a5[0];
    const float4 w5a = *(const float4*)(W5 + c * 2);
    const float4 w5b = *(const float4*)(W5 + c * 2 + 4);
    const float b50 = b5[0], b51 = b5[1];
    #pragma unroll
    for (int i = 0; i < 4; ++i) {
        float y0 = (acc[i][0] + bb.x) * BN_SCALE * g4.x + bn4.x;
        float y1 = (acc[i][1] + bb.y) * BN_SCALE * g4.y + bn4.y;
        float y2 = (acc[i][2] + bb.z) * BN_SCALE * g4.z + bn4.z;
        float y3 = (acc[i][3] + bb.w) * BN_SCALE * g4.w + bn4.w;
        y0 = (y0 >= 0.f) ? y0 : al * y0;
        y1 = (y1 >= 0.f) ? y1 : al * y1;
        y2 = (y2 >= 0.f) ? y2 : al * y2;
        y3 = (y3 >= 0.f) ? y3 : al * y3;
        float p0 = y0 * w5a.x + y1 * w5a.z + y2 * w5b.x + y3 * w5b.z;
        float p1 = y0 * w5a.y + y1 * w5a.w + y2 * w5b.y + y3 * w5b.w;
        #pragma unroll
        for (int off = 16; off > 0; off >>= 1) {
            p0 += __shfl_xor(p0, off, 32);
            p1 += __shfl_xor(p1, off, 32);
        }
        if (tc == 0) {
            const int r = row0 + tr * 4 + i;
            out[r * N_CLS + 0] = p0 + b50;
            out[r * N_CLS + 1] = p1 + b51;
        }
    }
}

extern "C" void kernel_launch(void* const* d_in, const int* in_sizes, int n_in,
                              void* d_out, int out_size, void* d_ws, size_t ws_size,
                              hipStream_t stream) {
    const float* feat  = (const float*)d_in[0];
    const float* lemb  = (const float*)d_in[1];
    const float* W1    = (const float*)d_in[2];
    const float* b1    = (const float*)d_in[3];
    const float* W2    = (const float*)d_in[4];
    const float* b2    = (const float*)d_in[5];
    const float* bn0g  = (const float*)d_in[6];
    const float* bn0b  = (const float*)d_in[7];
    const float* a3    = (const float*)d_in[8];
    const float* W3    = (const float*)d_in[9];
    const float* b3    = (const float*)d_in[10];
    const float* aconv = (const float*)d_in[35];
    const float* W4    = (const float*)d_in[36];
    const float* b4    = (const float*)d_in[37];
    const float* bn1g  = (const float*)d_in[38];
    const float* bn1b  = (const float*)d_in[39];
    const float* a5    = (const float*)d_in[40];
    const float* W5    = (const float*)d_in[41];
    const float* b5    = (const float*)d_in[42];
    const int*   labels = (const int*)d_in[43];
    const int*   esrc   = (const int*)d_in[44];

    // R2-exact workspace layout + swizzled weight tables appended
    char* ws = (char*)d_ws;
    float* bh  = (float*)ws;                       ws += sizeof(float) * N_NODES * F_IN;
    float* bt  = (float*)ws;                       ws += sizeof(float) * N_NODES * HD;
    float* bs  = (float*)ws;                       ws += sizeof(float) * N_NODES * HD;
    float* bag = (float*)ws;                       ws += sizeof(float) * N_NODES * HD;
    float* bh2 = (float*)ws;                       ws += sizeof(float) * N_NODES * HD;
    unsigned short* bqh = (unsigned short*)ws;     ws += sizeof(short) * N_NODES * HD;
    unsigned short* bkh = (unsigned short*)ws;     ws += sizeof(short) * N_NODES * HD;
    unsigned short* bvh = (unsigned short*)ws;     ws += sizeof(short) * N_NODES * HD;
    short* Wf0 = (short*)ws;                       ws += sizeof(short) * 4 * 20480;
    short* Wf1 = (short*)ws;                       ws += sizeof(short) * 4 * 16384;
    float* bE = bag;    // E[3][128] lives in bag until first kD_h (R2-proven aliasing)
    float* out = (float*)d_out;

    dim3 gT(N_NODES / 32);
    dim3 gT4(N_NODES / 32, 4);
    dim3 gD(N_NODES / 8, NHEAD);

    kE0<<<dim3(3), HD, 0, stream>>>(lemb, W2, b1, b2, bE);
    kSwiz4<5, F_IN><<<dim3(40, 4), 64, 0, stream>>>(
        (const float*)d_in[11], (const float*)d_in[13],
        (const float*)d_in[15], (const float*)d_in[17], Wf0);
    kSwiz4<4, HD><<<dim3(32, 4), 64, 0, stream>>>(
        (const float*)d_in[23], (const float*)d_in[25],
        (const float*)d_in[27], (const float*)d_in[29], Wf1);

    kA_t<F_IN><<<gT, 256, 0, stream>>>(feat, labels, bE, W1, bn0g, bn0b, a3, bt);
    kB_t<<<dim3(N_NODES / 16), 192, 0, stream>>>(bt, feat, W3, b3, bh);

    // conv layer 0 (K=142 -> LDSK=160, KC=5)
    kC_mf<F_IN, 160, 5><<<gT4, 256, 0, stream>>>(bh, Wf0,
        (const float*)d_in[12], (const float*)d_in[14],
        (const float*)d_in[16], (const float*)d_in[18],
        bqh, bkh, bvh, bs);
    kD_h<<<gD, 256, 0, stream>>>(bqh, bkh, bvh, esrc, bag);
    kE<<<dim3(N_NODES), HD, 0, stream>>>(bs, bag, (const float*)d_in[19], (const float*)d_in[20],
        (const float*)d_in[21], (const float*)d_in[22], aconv, bh2);

    // conv layer 1 (K=128 -> LDSK=128, KC=4)
    kC_mf<HD, 128, 4><<<gT4, 256, 0, stream>>>(bh2, Wf1,
        (const float*)d_in[24], (const float*)d_in[26],
        (const float*)d_in[28], (const float*)d_in[30],
        bqh, bkh, bvh, bs);
    kD_h<<<gD, 256, 0, stream>>>(bqh, bkh, bvh, esrc, bag);
    kE<<<dim3(N_NODES), HD, 0, stream>>>(bs, bag, (const float*)d_in[31], (const float*)d_in[32],
        (const float*)d_in[33], (const float*)d_in[34], aconv, bh2);

    kF_t<<<gT, 256, 0, stream>>>(bh2, W4, b4, bn1g, bn1b, a5, W5, b5, out);
}

// Round 8
// 344.253 us; speedup vs baseline: 2.4914x; 1.0793x over previous
//
#include <hip/hip_runtime.h>
#include <math.h>

#define N_NODES 20000
#define DEG 32
#define F_IN 142
#define HD 128
#define NHEAD 4
#define DHEAD 32
#define N_CLS 2

#define BN_SCALE 0.9999950000374997f
#define INV_SQRT_D 0.17677669529663687f

typedef short v8s __attribute__((ext_vector_type(8)));
typedef float v4f __attribute__((ext_vector_type(4)));

// ---- bf16 helpers (manual, RNE) ----
__device__ __forceinline__ unsigned short f2bf(float f) {
    unsigned u = __float_as_uint(f);
    return (unsigned short)((u + 0x7fffu + ((u >> 16) & 1u)) >> 16);
}
__device__ __forceinline__ unsigned pack2bf(float a, float b) {
    return (unsigned)f2bf(a) | ((unsigned)f2bf(b) << 16);
}
__device__ __forceinline__ float bf2f(unsigned short s) {
    return __uint_as_float((unsigned)s << 16);
}
__device__ __forceinline__ float bflo(unsigned u) { return __uint_as_float(u << 16); }
__device__ __forceinline__ float bfhi(unsigned u) { return __uint_as_float(u & 0xffff0000u); }

__device__ __forceinline__ v8s pack8(float4 f0, float4 f1) {
    union { v8s s; unsigned u[4]; } x;
    x.u[0] = pack2bf(f0.x, f0.y);
    x.u[1] = pack2bf(f0.z, f0.w);
    x.u[2] = pack2bf(f1.x, f1.y);
    x.u[3] = pack2bf(f1.z, f1.w);
    return x.s;
}

// ---------------- kE0: E[l] = lemb[l] @ W2 + b1 + b2 (l=0..2)  [R6-proven] ----------------
__global__ void kE0(const float* __restrict__ lemb, const float* __restrict__ W2,
                    const float* __restrict__ b1, const float* __restrict__ b2,
                    float* __restrict__ E) {
    __shared__ float sl[F_IN];
    int l = blockIdx.x, c = threadIdx.x;
    for (int f = c; f < F_IN; f += HD) sl[f] = lemb[l * F_IN + f];
    __syncthreads();
    float acc = b1[c] + b2[c];
    for (int f = 0; f < F_IN; ++f) acc += sl[f] * W2[f * HD + c];
    E[l * HD + c] = acc;
}

// ---------------- kSwiz4: fp32 W[K][128] -> bf16 B-fragment layout [R6-proven] ----------------
// Tile (nt,kc): lane L holds W[kc*32+(L>>4)*8+j][nt*16+(L&15)], j=0..7 contiguous.
template<int KC, int K>
__global__ void kSwiz4(const float* Wa, const float* Wb, const float* Wc,
                       const float* Wd, short* __restrict__ out) {
    const float* Wt[4] = {Wa, Wb, Wc, Wd};
    const float* W = Wt[blockIdx.y];
    const int tile = blockIdx.x;        // nt*KC + kc; grid.x = 8*KC
    const int kc = tile % KC, nt = tile / KC;
    const int L = threadIdx.x;
    const int n = nt * 16 + (L & 15);
    const int kb = kc * 32 + (L >> 4) * 8;
    short v[8] __attribute__((aligned(16)));
    #pragma unroll
    for (int j = 0; j < 8; ++j) {
        int k = kb + j;
        v[j] = (k < K) ? (short)f2bf(W[(size_t)k * HD + n]) : (short)0;
    }
    short* dst = out + (size_t)blockIdx.y * (8 * KC * 64 * 8) + ((size_t)tile * 64 + L) * 8;
    *(uint4*)dst = *(const uint4*)v;
}

// ---------------- kSwizW1: fp32 W1[142][128] -> bf16 B-frags, KC=5 (NEW, kSwiz shape) ----------------
__global__ void kSwizW1(const float* __restrict__ W, short* __restrict__ out) {
    const int tile = blockIdx.x;        // nt*5 + kc; grid.x = 40
    const int kc = tile % 5, nt = tile / 5;
    const int L = threadIdx.x;
    const int n = nt * 16 + (L & 15);
    const int kb = kc * 32 + (L >> 4) * 8;
    short v[8] __attribute__((aligned(16)));
    #pragma unroll
    for (int j = 0; j < 8; ++j) {
        int k = kb + j;
        v[j] = (k < F_IN) ? (short)f2bf(W[(size_t)k * HD + n]) : (short)0;
    }
    *(uint4*)(out + ((size_t)tile * 64 + L) * 8) = *(const uint4*)v;
}

// ---------------- kSwizW3: fp32 W3[128][142] -> bf16 B-frags, 9 n-tiles, KC=4 (NEW) ----------------
__global__ void kSwizW3(const float* __restrict__ W3, short* __restrict__ out) {
    const int tile = blockIdx.x;        // nt*4 + kc; grid.x = 36
    const int kc = tile & 3, nt = tile >> 2;
    const int L = threadIdx.x;
    const int n = nt * 16 + (L & 15);
    const int kb = kc * 32 + (L >> 4) * 8;
    short v[8] __attribute__((aligned(16)));
    #pragma unroll
    for (int j = 0; j < 8; ++j)
        v[j] = (n < F_IN) ? (short)f2bf(W3[(size_t)(kb + j) * F_IN + n]) : (short)0;
    *(uint4*)(out + ((size_t)tile * 64 + L) * 8) = *(const uint4*)v;
}

// ---------------- kAB: fused  t = PReLU(BN(feat@W1+E)),  h = feat + t@W3 + b3  (THE one change) ----------------
__global__ __launch_bounds__(256) void kAB_m(const float* __restrict__ feat,
        const short* __restrict__ W1f, const short* __restrict__ W3f,
        const int* __restrict__ labels, const float* __restrict__ E,
        const float* __restrict__ bng, const float* __restrict__ bnb,
        const float* __restrict__ a3, const float* __restrict__ b3,
        float* __restrict__ h) {
    __shared__ float4 sAv[32 * 164 / 4];
    __shared__ uint4  sTv[32 * 136 / 8];
    __shared__ int sLab[32];
    float* sA = (float*)sAv;
    unsigned short* sT = (unsigned short*)sTv;
    const int tid = threadIdx.x;
    const int row0 = blockIdx.x * 32;
    for (int idx = tid; idx < 32 * F_IN; idx += 256) {
        int r = idx / F_IN, c = idx - r * F_IN;
        sA[r * 164 + c] = feat[(size_t)(row0 + r) * F_IN + c];
    }
    {   const int ZC = 160 - F_IN;
        for (int idx = tid; idx < 32 * ZC; idx += 256) {
            int r = idx / ZC, c = idx - r * ZC;
            sA[r * 164 + F_IN + c] = 0.f;
        }
    }
    if (tid < 32) sLab[tid] = labels[row0 + tid];
    __syncthreads();

    const int lane = tid & 63, w = tid >> 6;
    const int m = lane & 15, q = lane >> 4;
    const int nt0 = w * 2, nt1 = nt0 + 1;

    // ---- phase 1: t = feat @ W1 (K=160) ----
    v4f acc00 = {0.f,0.f,0.f,0.f}, acc01 = acc00, acc10 = acc00, acc11 = acc00;
    #pragma unroll
    for (int kc = 0; kc < 5; ++kc) {
        const float* r0 = sA + m * 164 + kc * 32 + q * 8;
        const float* r1 = sA + (16 + m) * 164 + kc * 32 + q * 8;
        v8s a0 = pack8(*(const float4*)r0, *(const float4*)(r0 + 4));
        v8s a1 = pack8(*(const float4*)r1, *(const float4*)(r1 + 4));
        v8s b0 = *(const v8s*)(W1f + ((size_t)((nt0 * 5 + kc) * 64 + lane)) * 8);
        v8s b1 = *(const v8s*)(W1f + ((size_t)((nt1 * 5 + kc) * 64 + lane)) * 8);
        acc00 = __builtin_amdgcn_mfma_f32_16x16x32_bf16(a0, b0, acc00, 0, 0, 0);
        acc01 = __builtin_amdgcn_mfma_f32_16x16x32_bf16(a0, b1, acc01, 0, 0, 0);
        acc10 = __builtin_amdgcn_mfma_f32_16x16x32_bf16(a1, b0, acc10, 0, 0, 0);
        acc11 = __builtin_amdgcn_mfma_f32_16x16x32_bf16(a1, b1, acc11, 0, 0, 0);
    }
    const int c0 = w * 32 + m, c1 = c0 + 16;
    {   // phase-1 epilogue: BN + PReLU, t -> LDS bf16
        const float g0 = bng[c0] * BN_SCALE, g1 = bng[c1] * BN_SCALE;
        const float bb0 = bnb[c0], bb1 = bnb[c1];
        const float al = a3[0];
        #pragma unroll
        for (int rt = 0; rt < 2; ++rt) {
            v4f A0 = rt ? acc10 : acc00;
            v4f A1 = rt ? acc11 : acc01;
            #pragma unroll
            for (int i = 0; i < 4; ++i) {
                const int r = rt * 16 + q * 4 + i;
                const int lab = sLab[r];
                float y0 = (A0[i] + E[lab * HD + c0]) * g0 + bb0;
                float y1 = (A1[i] + E[lab * HD + c1]) * g1 + bb1;
                y0 = (y0 >= 0.f) ? y0 : al * y0;
                y1 = (y1 >= 0.f) ? y1 : al * y1;
                sT[r * 136 + c0] = f2bf(y0);
                sT[r * 136 + c1] = f2bf(y1);
            }
        }
    }
    __syncthreads();

    // ---- phase 2: h = feat + t @ W3 + b3 (K=128, N=142 in 9 n-tiles) ----
    v4f d00 = {0.f,0.f,0.f,0.f}, d01 = d00, d10 = d00, d11 = d00, e0 = d00, e1 = d00;
    #pragma unroll
    for (int kc = 0; kc < 4; ++kc) {
        v8s a0 = *(const v8s*)(sT + m * 136 + kc * 32 + q * 8);
        v8s a1 = *(const v8s*)(sT + (16 + m) * 136 + kc * 32 + q * 8);
        v8s b0 = *(const v8s*)(W3f + ((size_t)((nt0 * 4 + kc) * 64 + lane)) * 8);
        v8s b1 = *(const v8s*)(W3f + ((size_t)((nt1 * 4 + kc) * 64 + lane)) * 8);
        d00 = __builtin_amdgcn_mfma_f32_16x16x32_bf16(a0, b0, d00, 0, 0, 0);
        d01 = __builtin_amdgcn_mfma_f32_16x16x32_bf16(a0, b1, d01, 0, 0, 0);
        d10 = __builtin_amdgcn_mfma_f32_16x16x32_bf16(a1, b0, d10, 0, 0, 0);
        d11 = __builtin_amdgcn_mfma_f32_16x16x32_bf16(a1, b1, d11, 0, 0, 0);
        if (w == 3) {   // wave-uniform: wave 3 also handles n-tile 8 (cols 128..143)
            v8s b2 = *(const v8s*)(W3f + ((size_t)((8 * 4 + kc) * 64 + lane)) * 8);
            e0 = __builtin_amdgcn_mfma_f32_16x16x32_bf16(a0, b2, e0, 0, 0, 0);
            e1 = __builtin_amdgcn_mfma_f32_16x16x32_bf16(a1, b2, e1, 0, 0, 0);
        }
    }
    const float b30 = b3[c0], b31 = b3[c1];
    #pragma unroll
    for (int rt = 0; rt < 2; ++rt) {
        v4f D0 = rt ? d10 : d00;
        v4f D1 = rt ? d11 : d01;
        #pragma unroll
        for (int i = 0; i < 4; ++i) {
            const int r = row0 + rt * 16 + q * 4 + i;
            h[(size_t)r * F_IN + c0] = feat[(size_t)r * F_IN + c0] + D0[i] + b30;
            h[(size_t)r * F_IN + c1] = feat[(size_t)r * F_IN + c1] + D1[i] + b31;
        }
    }
    if (w == 3) {
        const int c2 = 128 + m;
        if (c2 < F_IN) {
            const float b32 = b3[c2];
            #pragma unroll
            for (int i = 0; i < 4; ++i) {
                const int ra = row0 + q * 4 + i;
                const int rb = ra + 16;
                h[(size_t)ra * F_IN + c2] = feat[(size_t)ra * F_IN + c2] + e0[i] + b32;
                h[(size_t)rb * F_IN + c2] = feat[(size_t)rb * F_IN + c2] + e1[i] + b32;
            }
        }
    }
}

// ---------------- fp32 tiled-GEMM core [R6-proven] ----------------
template<int K>
__device__ __forceinline__ void gemm_acc(const float* __restrict__ W,
                                         const float* sA, float* sW,
                                         float acc[4][4], int tid, int tr, int tc) {
    int k0 = 0;
    for (; k0 + 16 <= K; k0 += 16) {
        __syncthreads();
        #pragma unroll
        for (int i = 0; i < 8; ++i)
            sW[tid + i * 256] = W[k0 * HD + tid + i * 256];
        __syncthreads();
        #pragma unroll
        for (int kk = 0; kk < 16; ++kk) {
            const float4 wv = *(const float4*)(sW + kk * HD + tc * 4);
            #pragma unroll
            for (int i = 0; i < 4; ++i) {
                const float av = sA[(tr * 4 + i) * K + k0 + kk];
                acc[i][0] = fmaf(av, wv.x, acc[i][0]);
                acc[i][1] = fmaf(av, wv.y, acc[i][1]);
                acc[i][2] = fmaf(av, wv.z, acc[i][2]);
                acc[i][3] = fmaf(av, wv.w, acc[i][3]);
            }
        }
    }
    if (k0 < K) {
        const int kb = K - k0;
        __syncthreads();
        for (int i = tid; i < kb * HD; i += 256)
            sW[i] = W[k0 * HD + i];
        __syncthreads();
        for (int kk = 0; kk < kb; ++kk) {
            const float4 wv = *(const float4*)(sW + kk * HD + tc * 4);
            #pragma unroll
            for (int i = 0; i < 4; ++i) {
                const float av = sA[(tr * 4 + i) * K + k0 + kk];
                acc[i][0] = fmaf(av, wv.x, acc[i][0]);
                acc[i][1] = fmaf(av, wv.y, acc[i][1]);
                acc[i][2] = fmaf(av, wv.z, acc[i][2]);
                acc[i][3] = fmaf(av, wv.w, acc[i][3]);
            }
        }
    }
}

// ---------------- kC (MFMA) [R6-proven, byte-identical] ----------------
template<int K, int LDSK, int KC>
__global__ __launch_bounds__(256) void kC_mf(const float* __restrict__ A,
        const short* __restrict__ WfBase,
        const float* __restrict__ bq, const float* __restrict__ bk,
        const float* __restrict__ bv, const float* __restrict__ bs,
        unsigned short* __restrict__ qh, unsigned short* __restrict__ kh,
        unsigned short* __restrict__ vh, float* __restrict__ sOut) {
    __shared__ float4 sAv[32 * LDSK / 4];
    float* sA = (float*)sAv;
    const int tid = threadIdx.x;
    const int row0 = blockIdx.x * 32;
    const int mat = blockIdx.y;
    for (int idx = tid; idx < 32 * K; idx += 256) {
        int r = idx / K, c = idx - r * K;
        sA[r * LDSK + c] = A[(size_t)(row0 + r) * K + c];
    }
    if (K < KC * 32) {
        const int ZC = KC * 32 - K;
        for (int idx = tid; idx < 32 * ZC; idx += 256) {
            int r = idx / ZC, c = idx - r * ZC;
            sA[r * LDSK + K + c] = 0.f;
        }
    }
    __syncthreads();

    const short* Wf = WfBase + (size_t)mat * (KC * 4096);
    const float* bias = (mat == 0) ? bq : (mat == 1) ? bk : (mat == 2) ? bv : bs;
    const int lane = tid & 63, w = tid >> 6;
    const int m = lane & 15, q = lane >> 4;
    const int nt0 = w * 2, nt1 = nt0 + 1;
    v4f acc00 = {0.f,0.f,0.f,0.f}, acc01 = acc00, acc10 = acc00, acc11 = acc00;
    #pragma unroll
    for (int kc = 0; kc < KC; ++kc) {
        const float* r0 = sA + m * LDSK + kc * 32 + q * 8;
        const float* r1 = sA + (16 + m) * LDSK + kc * 32 + q * 8;
        v8s a0 = pack8(*(const float4*)r0, *(const float4*)(r0 + 4));
        v8s a1 = pack8(*(const float4*)r1, *(const float4*)(r1 + 4));
        v8s b0 = *(const v8s*)(Wf + ((size_t)((nt0 * KC + kc) * 64 + lane)) * 8);
        v8s b1 = *(const v8s*)(Wf + ((size_t)((nt1 * KC + kc) * 64 + lane)) * 8);
        acc00 = __builtin_amdgcn_mfma_f32_16x16x32_bf16(a0, b0, acc00, 0, 0, 0);
        acc01 = __builtin_amdgcn_mfma_f32_16x16x32_bf16(a0, b1, acc01, 0, 0, 0);
        acc10 = __builtin_amdgcn_mfma_f32_16x16x32_bf16(a1, b0, acc10, 0, 0, 0);
        acc11 = __builtin_amdgcn_mfma_f32_16x16x32_bf16(a1, b1, acc11, 0, 0, 0);
    }
    const int c0 = w * 32 + m, c1 = c0 + 16;
    const float b0v = bias[c0], b1v = bias[c1];
    if (mat < 3) {
        unsigned short* outh = (mat == 0) ? qh : (mat == 1) ? kh : vh;
        unsigned short* outw = outh + ((size_t)w * N_NODES + row0) * DHEAD;
        #pragma unroll
        for (int rt = 0; rt < 2; ++rt) {
            v4f A0 = rt ? acc10 : acc00;
            v4f A1 = rt ? acc11 : acc01;
            #pragma unroll
            for (int i = 0; i < 4; ++i) {
                const int r = rt * 16 + q * 4 + i;
                outw[(size_t)r * DHEAD + m]      = f2bf(A0[i] + b0v);
                outw[(size_t)r * DHEAD + 16 + m] = f2bf(A1[i] + b1v);
            }
        }
    } else {
        #pragma unroll
        for (int rt = 0; rt < 2; ++rt) {
            v4f A0 = rt ? acc10 : acc00;
            v4f A1 = rt ? acc11 : acc01;
            #pragma unroll
            for (int i = 0; i < 4; ++i) {
                const int r = rt * 16 + q * 4 + i;
                sOut[(size_t)(row0 + r) * HD + c0] = A0[i] + b0v;
                sOut[(size_t)(row0 + r) * HD + c1] = A1[i] + b1v;
            }
        }
    }
}

// ---------------- kD: head-split attention, bf16 gathers [R6-proven] ----------------
__global__ __launch_bounds__(256) void kD_h(const unsigned short* __restrict__ qh,
        const unsigned short* __restrict__ kh, const unsigned short* __restrict__ vh,
        const int* __restrict__ esrc, float* __restrict__ agg) {
    __shared__ float sk[8][DHEAD];
    __shared__ int ssrc[8][DEG];
    __shared__ float sa[8][DEG];
    const int h = blockIdx.y;
    const int n0 = blockIdx.x * 8;
    const int t = threadIdx.x;
    const int j = t >> 5, e = t & 31;

    ssrc[j][e] = esrc[n0 * DEG + t];
    if (t < 128) {
        unsigned u = *((const unsigned*)(kh + ((size_t)h * N_NODES + n0) * DHEAD) + t);
        float* skf = &sk[0][0];
        skf[2 * t]     = bflo(u);
        skf[2 * t + 1] = bfhi(u);
    }
    __syncthreads();

    const int src = ssrc[j][e];
    const uint4* qp = (const uint4*)(qh + ((size_t)h * N_NODES + src) * DHEAD);
    const float* kj = sk[j];
    float sc = 0.f;
    #pragma unroll
    for (int i = 0; i < 4; ++i) {
        uint4 u = qp[i];
        sc = fmaf(bflo(u.x), kj[i * 8 + 0], sc);
        sc = fmaf(bfhi(u.x), kj[i * 8 + 1], sc);
        sc = fmaf(bflo(u.y), kj[i * 8 + 2], sc);
        sc = fmaf(bfhi(u.y), kj[i * 8 + 3], sc);
        sc = fmaf(bflo(u.z), kj[i * 8 + 4], sc);
        sc = fmaf(bfhi(u.z), kj[i * 8 + 5], sc);
        sc = fmaf(bflo(u.w), kj[i * 8 + 6], sc);
        sc = fmaf(bfhi(u.w), kj[i * 8 + 7], sc);
    }
    sc *= INV_SQRT_D;
    float m = sc;
    #pragma unroll
    for (int off = 16; off > 0; off >>= 1)
        m = fmaxf(m, __shfl_xor(m, off, 32));
    float p = expf(sc - m);
    float ssum = p;
    #pragma unroll
    for (int off = 16; off > 0; off >>= 1)
        ssum += __shfl_xor(ssum, off, 32);
    sa[j][e] = p / ssum;
    __syncthreads();

    const int d = t & 31;
    const unsigned short* vbase = vh + (size_t)h * N_NODES * DHEAD + d;
    float acc = 0.f;
    #pragma unroll
    for (int e2 = 0; e2 < DEG; ++e2) {
        const int s2 = ssrc[j][e2];
        acc = fmaf(bf2f(vbase[(size_t)s2 * DHEAD]), sa[j][e2], acc);
    }
    agg[(size_t)(n0 + j) * HD + h * DHEAD + d] = acc;
}

// ---------------- fast 128-thread block reduce [R6-proven] ----------------
__device__ __forceinline__ float blockSum128(float v, float* s2, int tid) {
    #pragma unroll
    for (int o = 32; o > 0; o >>= 1) v += __shfl_xor(v, o, 64);
    if ((tid & 63) == 0) s2[tid >> 6] = v;
    __syncthreads();
    float r = s2[0] + s2[1];
    __syncthreads();
    return r;
}

// ---------------- kE: gate + gated mix + LayerNorm + PReLU, fp32 [R6-proven] ----------------
__global__ void kE(const float* __restrict__ skip, const float* __restrict__ agg,
                   const float* __restrict__ Wg, const float* __restrict__ bg,
                   const float* __restrict__ lng, const float* __restrict__ lnb,
                   const float* __restrict__ ac,
                   float* __restrict__ hout) {
    __shared__ float red[2];
    int n = blockIdx.x, c = threadIdx.x;
    float sk = skip[n * HD + c], ag = agg[n * HD + c];
    float part = sk * Wg[c] + ag * Wg[HD + c] + (sk - ag) * Wg[2 * HD + c];
    float z = blockSum128(part, red, c) + bg[0];
    float g = 1.f / (1.f + expf(-z));
    float r = g * sk + (1.f - g) * ag;
    float mean = blockSum128(r, red, c) * (1.f / HD);
    float dv = r - mean;
    float var = blockSum128(dv * dv, red, c) * (1.f / HD);
    float y = dv * rsqrtf(var + 1e-5f) * lng[c] + lnb[c];
    float a = ac[0];
    hout[n * HD + c] = (y >= 0.f) ? y : a * y;
}

// ---------------- kF: out = PReLU(BN(h@W4 + b4)) @ W5 + b5, fp32 [R6-proven] ----------------
__global__ __launch_bounds__(256) void kF_t(const float* __restrict__ A,
        const float* __restrict__ W4, const float* __restrict__ b4,
        const float* __restrict__ bng, const float* __restrict__ bnb,
        const float* __restrict__ a5, const float* __restrict__ W5,
        const float* __restrict__ b5, float* __restrict__ out) {
    __shared__ float sA[32 * HD];
    __shared__ float sW[16 * HD];
    const int tid = threadIdx.x, tr = tid >> 5, tc = tid & 31;
    const int row0 = blockIdx.x * 32;
    for (int i = tid; i < 32 * HD; i += 256) sA[i] = A[(size_t)row0 * HD + i];
    float acc[4][4] = {};
    gemm_acc<HD>(W4, sA, sW, acc, tid, tr, tc);
    const int c = tc * 4;
    const float4 bb = *(const float4*)(b4 + c);
    const float4 g4 = *(const float4*)(bng + c);
    const float4 bn4 = *(const float4*)(bnb + c);
    const float al = a5[0];
    const float4 w5a = *(const float4*)(W5 + c * 2);
    const float4 w5b = *(const float4*)(W5 + c * 2 + 4);
    const float b50 = b5[0], b51 = b5[1];
    #pragma unroll
    for (int i = 0; i < 4; ++i) {
        float y0 = (acc[i][0] + bb.x) * BN_SCALE * g4.x + bn4.x;
        float y1 = (acc[i][1] + bb.y) * BN_SCALE * g4.y + bn4.y;
        float y2 = (acc[i][2] + bb.z) * BN_SCALE * g4.z + bn4.z;
        float y3 = (acc[i][3] + bb.w) * BN_SCALE * g4.w + bn4.w;
        y0 = (y0 >= 0.f) ? y0 : al * y0;
        y1 = (y1 >= 0.f) ? y1 : al * y1;
        y2 = (y2 >= 0.f) ? y2 : al * y2;
        y3 = (y3 >= 0.f) ? y3 : al * y3;
        float p0 = y0 * w5a.x + y1 * w5a.z + y2 * w5b.x + y3 * w5b.z;
        float p1 = y0 * w5a.y + y1 * w5a.w + y2 * w5b.y + y3 * w5b.w;
        #pragma unroll
        for (int off = 16; off > 0; off >>= 1) {
            p0 += __shfl_xor(p0, off, 32);
            p1 += __shfl_xor(p1, off, 32);
        }
        if (tc == 0) {
            const int r = row0 + tr * 4 + i;
            out[r * N_CLS + 0] = p0 + b50;
            out[r * N_CLS + 1] = p1 + b51;
        }
    }
}

extern "C" void kernel_launch(void* const* d_in, const int* in_sizes, int n_in,
                              void* d_out, int out_size, void* d_ws, size_t ws_size,
                              hipStream_t stream) {
    const float* feat  = (const float*)d_in[0];
    const float* lemb  = (const float*)d_in[1];
    const float* W1    = (const float*)d_in[2];
    const float* b1    = (const float*)d_in[3];
    const float* W2    = (const float*)d_in[4];
    const float* b2    = (const float*)d_in[5];
    const float* bn0g  = (const float*)d_in[6];
    const float* bn0b  = (const float*)d_in[7];
    const float* a3    = (const float*)d_in[8];
    const float* W3    = (const float*)d_in[9];
    const float* b3    = (const float*)d_in[10];
    const float* aconv = (const float*)d_in[35];
    const float* W4    = (const float*)d_in[36];
    const float* b4    = (const float*)d_in[37];
    const float* bn1g  = (const float*)d_in[38];
    const float* bn1b  = (const float*)d_in[39];
    const float* a5    = (const float*)d_in[40];
    const float* W5    = (const float*)d_in[41];
    const float* b5    = (const float*)d_in[42];
    const int*   labels = (const int*)d_in[43];
    const int*   esrc   = (const int*)d_in[44];

    // R6-style workspace layout + W1f/W3f tables appended (bt dropped: kAB writes bh directly)
    char* ws = (char*)d_ws;
    float* bh  = (float*)ws;                       ws += sizeof(float) * N_NODES * F_IN;
    float* bs  = (float*)ws;                       ws += sizeof(float) * N_NODES * HD;
    float* bag = (float*)ws;                       ws += sizeof(float) * N_NODES * HD;
    float* bh2 = (float*)ws;                       ws += sizeof(float) * N_NODES * HD;
    unsigned short* bqh = (unsigned short*)ws;     ws += sizeof(short) * N_NODES * HD;
    unsigned short* bkh = (unsigned short*)ws;     ws += sizeof(short) * N_NODES * HD;
    unsigned short* bvh = (unsigned short*)ws;     ws += sizeof(short) * N_NODES * HD;
    short* Wf0 = (short*)ws;                       ws += sizeof(short) * 4 * 20480;  // q0,k0,v0,s0
    short* Wf1 = (short*)ws;                       ws += sizeof(short) * 4 * 16384;  // q1,k1,v1,s1
    short* W1f = (short*)ws;                       ws += sizeof(short) * 20480;      // W1
    short* W3f = (short*)ws;                       ws += sizeof(short) * 36 * 512;   // W3, 9 nt x 4 kc
    float* bE = bag;    // E[3][128] lives in bag until first kD_h (proven aliasing)
    float* out = (float*)d_out;

    dim3 gT(N_NODES / 32);
    dim3 gT4(N_NODES / 32, 4);
    dim3 gD(N_NODES / 8, NHEAD);

    kE0<<<dim3(3), HD, 0, stream>>>(lemb, W2, b1, b2, bE);
    kSwiz4<5, F_IN><<<dim3(40, 4), 64, 0, stream>>>(
        (const float*)d_in[11], (const float*)d_in[13],
        (const float*)d_in[15], (const float*)d_in[17], Wf0);
    kSwiz4<4, HD><<<dim3(32, 4), 64, 0, stream>>>(
        (const float*)d_in[23], (const float*)d_in[25],
        (const float*)d_in[27], (const float*)d_in[29], Wf1);
    kSwizW1<<<dim3(40), 64, 0, stream>>>(W1, W1f);
    kSwizW3<<<dim3(36), 64, 0, stream>>>(W3, W3f);

    kAB_m<<<gT, 256, 0, stream>>>(feat, W1f, W3f, labels, bE, bn0g, bn0b, a3, b3, bh);

    // conv layer 0 (K=142 -> LDSK=160, KC=5)  [R6-exact]
    kC_mf<F_IN, 160, 5><<<gT4, 256, 0, stream>>>(bh, Wf0,
        (const float*)d_in[12], (const float*)d_in[14],
        (const float*)d_in[16], (const float*)d_in[18],
        bqh, bkh, bvh, bs);
    kD_h<<<gD, 256, 0, stream>>>(bqh, bkh, bvh, esrc, bag);
    kE<<<dim3(N_NODES), HD, 0, stream>>>(bs, bag, (const float*)d_in[19], (const float*)d_in[20],
        (const float*)d_in[21], (const float*)d_in[22], aconv, bh2);

    // conv layer 1 (K=128 -> LDSK=128, KC=4)  [R6-exact]
    kC_mf<HD, 128, 4><<<gT4, 256, 0, stream>>>(bh2, Wf1,
        (const float*)d_in[24], (const float*)d_in[26],
        (const float*)d_in[28], (const float*)d_in[30],
        bqh, bkh, bvh, bs);
    kD_h<<<gD, 256, 0, stream>>>(bqh, bkh, bvh, esrc, bag);
    kE<<<dim3(N_NODES), HD, 0, stream>>>(bs, bag, (const float*)d_in[31], (const float*)d_in[32],
        (const float*)d_in[33], (const float*)d_in[34], aconv, bh2);

    kF_t<<<gT, 256, 0, stream>>>(bh2, W4, b4, bn1g, bn1b, a5, W5, b5, out);
}

// Round 9
// 328.543 us; speedup vs baseline: 2.6106x; 1.0478x over previous
//
#include <hip/hip_runtime.h>
#include <math.h>

#define N_NODES 20000
#define DEG 32
#define F_IN 142
#define HD 128
#define NHEAD 4
#define DHEAD 32
#define N_CLS 2

#define BN_SCALE 0.9999950000374997f
#define INV_SQRT_D 0.17677669529663687f

typedef short v8s __attribute__((ext_vector_type(8)));
typedef float v4f __attribute__((ext_vector_type(4)));

// ---- bf16 helpers (manual, RNE) ----
__device__ __forceinline__ unsigned short f2bf(float f) {
    unsigned u = __float_as_uint(f);
    return (unsigned short)((u + 0x7fffu + ((u >> 16) & 1u)) >> 16);
}
__device__ __forceinline__ unsigned pack2bf(float a, float b) {
    return (unsigned)f2bf(a) | ((unsigned)f2bf(b) << 16);
}
__device__ __forceinline__ float bf2f(unsigned short s) {
    return __uint_as_float((unsigned)s << 16);
}
__device__ __forceinline__ float bflo(unsigned u) { return __uint_as_float(u << 16); }
__device__ __forceinline__ float bfhi(unsigned u) { return __uint_as_float(u & 0xffff0000u); }

__device__ __forceinline__ v8s pack8(float4 f0, float4 f1) {
    union { v8s s; unsigned u[4]; } x;
    x.u[0] = pack2bf(f0.x, f0.y);
    x.u[1] = pack2bf(f0.z, f0.w);
    x.u[2] = pack2bf(f1.x, f1.y);
    x.u[3] = pack2bf(f1.z, f1.w);
    return x.s;
}

// ---------------- kE0: E[l] = lemb[l] @ W2 + b1 + b2 (l=0..2)  [proven] ----------------
__global__ void kE0(const float* __restrict__ lemb, const float* __restrict__ W2,
                    const float* __restrict__ b1, const float* __restrict__ b2,
                    float* __restrict__ E) {
    __shared__ float sl[F_IN];
    int l = blockIdx.x, c = threadIdx.x;
    for (int f = c; f < F_IN; f += HD) sl[f] = lemb[l * F_IN + f];
    __syncthreads();
    float acc = b1[c] + b2[c];
    for (int f = 0; f < F_IN; ++f) acc += sl[f] * W2[f * HD + c];
    E[l * HD + c] = acc;
}

// ---------------- kSwiz4: fp32 W[K][128] -> bf16 B-fragment layout (4 matrices) [proven] ----------------
template<int KC, int K>
__global__ void kSwiz4(const float* Wa, const float* Wb, const float* Wc,
                       const float* Wd, short* __restrict__ out) {
    const float* Wt[4] = {Wa, Wb, Wc, Wd};
    const float* W = Wt[blockIdx.y];
    const int tile = blockIdx.x;        // nt*KC + kc; grid.x = 8*KC
    const int kc = tile % KC, nt = tile / KC;
    const int L = threadIdx.x;
    const int n = nt * 16 + (L & 15);
    const int kb = kc * 32 + (L >> 4) * 8;
    short v[8] __attribute__((aligned(16)));
    #pragma unroll
    for (int j = 0; j < 8; ++j) {
        int k = kb + j;
        v[j] = (k < K) ? (short)f2bf(W[(size_t)k * HD + n]) : (short)0;
    }
    short* dst = out + (size_t)blockIdx.y * (8 * KC * 64 * 8) + ((size_t)tile * 64 + L) * 8;
    *(uint4*)dst = *(const uint4*)v;
}

// ---------------- kSwiz1: single matrix W[K][128] -> frags [proven shape] ----------------
template<int KC, int K>
__global__ void kSwiz1(const float* __restrict__ W, short* __restrict__ out) {
    const int tile = blockIdx.x;        // nt*KC + kc; grid.x = 8*KC
    const int kc = tile % KC, nt = tile / KC;
    const int L = threadIdx.x;
    const int n = nt * 16 + (L & 15);
    const int kb = kc * 32 + (L >> 4) * 8;
    short v[8] __attribute__((aligned(16)));
    #pragma unroll
    for (int j = 0; j < 8; ++j) {
        int k = kb + j;
        v[j] = (k < K) ? (short)f2bf(W[(size_t)k * HD + n]) : (short)0;
    }
    *(uint4*)(out + ((size_t)tile * 64 + L) * 8) = *(const uint4*)v;
}

// ---------------- kSwizW3: fp32 W3[128][142] -> bf16 B-frags, 9 n-tiles, KC=4 [proven] ----------------
__global__ void kSwizW3(const float* __restrict__ W3, short* __restrict__ out) {
    const int tile = blockIdx.x;        // nt*4 + kc; grid.x = 36
    const int kc = tile & 3, nt = tile >> 2;
    const int L = threadIdx.x;
    const int n = nt * 16 + (L & 15);
    const int kb = kc * 32 + (L >> 4) * 8;
    short v[8] __attribute__((aligned(16)));
    #pragma unroll
    for (int j = 0; j < 8; ++j)
        v[j] = (n < F_IN) ? (short)f2bf(W3[(size_t)(kb + j) * F_IN + n]) : (short)0;
    *(uint4*)(out + ((size_t)tile * 64 + L) * 8) = *(const uint4*)v;
}

// ---------------- kAB: fused t = PReLU(BN(feat@W1+E)), h = feat + t@W3 + b3 [R8-proven] ----------------
__global__ __launch_bounds__(256) void kAB_m(const float* __restrict__ feat,
        const short* __restrict__ W1f, const short* __restrict__ W3f,
        const int* __restrict__ labels, const float* __restrict__ E,
        const float* __restrict__ bng, const float* __restrict__ bnb,
        const float* __restrict__ a3, const float* __restrict__ b3,
        float* __restrict__ h) {
    __shared__ float4 sAv[32 * 164 / 4];
    __shared__ uint4  sTv[32 * 136 / 8];
    __shared__ int sLab[32];
    float* sA = (float*)sAv;
    unsigned short* sT = (unsigned short*)sTv;
    const int tid = threadIdx.x;
    const int row0 = blockIdx.x * 32;
    for (int idx = tid; idx < 32 * F_IN; idx += 256) {
        int r = idx / F_IN, c = idx - r * F_IN;
        sA[r * 164 + c] = feat[(size_t)(row0 + r) * F_IN + c];
    }
    {   const int ZC = 160 - F_IN;
        for (int idx = tid; idx < 32 * ZC; idx += 256) {
            int r = idx / ZC, c = idx - r * ZC;
            sA[r * 164 + F_IN + c] = 0.f;
        }
    }
    if (tid < 32) sLab[tid] = labels[row0 + tid];
    __syncthreads();

    const int lane = tid & 63, w = tid >> 6;
    const int m = lane & 15, q = lane >> 4;
    const int nt0 = w * 2, nt1 = nt0 + 1;

    v4f acc00 = {0.f,0.f,0.f,0.f}, acc01 = acc00, acc10 = acc00, acc11 = acc00;
    #pragma unroll
    for (int kc = 0; kc < 5; ++kc) {
        const float* r0 = sA + m * 164 + kc * 32 + q * 8;
        const float* r1 = sA + (16 + m) * 164 + kc * 32 + q * 8;
        v8s a0 = pack8(*(const float4*)r0, *(const float4*)(r0 + 4));
        v8s a1 = pack8(*(const float4*)r1, *(const float4*)(r1 + 4));
        v8s b0 = *(const v8s*)(W1f + ((size_t)((nt0 * 5 + kc) * 64 + lane)) * 8);
        v8s b1 = *(const v8s*)(W1f + ((size_t)((nt1 * 5 + kc) * 64 + lane)) * 8);
        acc00 = __builtin_amdgcn_mfma_f32_16x16x32_bf16(a0, b0, acc00, 0, 0, 0);
        acc01 = __builtin_amdgcn_mfma_f32_16x16x32_bf16(a0, b1, acc01, 0, 0, 0);
        acc10 = __builtin_amdgcn_mfma_f32_16x16x32_bf16(a1, b0, acc10, 0, 0, 0);
        acc11 = __builtin_amdgcn_mfma_f32_16x16x32_bf16(a1, b1, acc11, 0, 0, 0);
    }
    const int c0 = w * 32 + m, c1 = c0 + 16;
    {
        const float g0 = bng[c0] * BN_SCALE, g1 = bng[c1] * BN_SCALE;
        const float bb0 = bnb[c0], bb1 = bnb[c1];
        const float al = a3[0];
        #pragma unroll
        for (int rt = 0; rt < 2; ++rt) {
            v4f A0 = rt ? acc10 : acc00;
            v4f A1 = rt ? acc11 : acc01;
            #pragma unroll
            for (int i = 0; i < 4; ++i) {
                const int r = rt * 16 + q * 4 + i;
                const int lab = sLab[r];
                float y0 = (A0[i] + E[lab * HD + c0]) * g0 + bb0;
                float y1 = (A1[i] + E[lab * HD + c1]) * g1 + bb1;
                y0 = (y0 >= 0.f) ? y0 : al * y0;
                y1 = (y1 >= 0.f) ? y1 : al * y1;
                sT[r * 136 + c0] = f2bf(y0);
                sT[r * 136 + c1] = f2bf(y1);
            }
        }
    }
    __syncthreads();

    v4f d00 = {0.f,0.f,0.f,0.f}, d01 = d00, d10 = d00, d11 = d00, e0 = d00, e1 = d00;
    #pragma unroll
    for (int kc = 0; kc < 4; ++kc) {
        v8s a0 = *(const v8s*)(sT + m * 136 + kc * 32 + q * 8);
        v8s a1 = *(const v8s*)(sT + (16 + m) * 136 + kc * 32 + q * 8);
        v8s b0 = *(const v8s*)(W3f + ((size_t)((nt0 * 4 + kc) * 64 + lane)) * 8);
        v8s b1 = *(const v8s*)(W3f + ((size_t)((nt1 * 4 + kc) * 64 + lane)) * 8);
        d00 = __builtin_amdgcn_mfma_f32_16x16x32_bf16(a0, b0, d00, 0, 0, 0);
        d01 = __builtin_amdgcn_mfma_f32_16x16x32_bf16(a0, b1, d01, 0, 0, 0);
        d10 = __builtin_amdgcn_mfma_f32_16x16x32_bf16(a1, b0, d10, 0, 0, 0);
        d11 = __builtin_amdgcn_mfma_f32_16x16x32_bf16(a1, b1, d11, 0, 0, 0);
        if (w == 3) {
            v8s b2 = *(const v8s*)(W3f + ((size_t)((8 * 4 + kc) * 64 + lane)) * 8);
            e0 = __builtin_amdgcn_mfma_f32_16x16x32_bf16(a0, b2, e0, 0, 0, 0);
            e1 = __builtin_amdgcn_mfma_f32_16x16x32_bf16(a1, b2, e1, 0, 0, 0);
        }
    }
    const float b30 = b3[c0], b31 = b3[c1];
    #pragma unroll
    for (int rt = 0; rt < 2; ++rt) {
        v4f D0 = rt ? d10 : d00;
        v4f D1 = rt ? d11 : d01;
        #pragma unroll
        for (int i = 0; i < 4; ++i) {
            const int r = row0 + rt * 16 + q * 4 + i;
            h[(size_t)r * F_IN + c0] = feat[(size_t)r * F_IN + c0] + D0[i] + b30;
            h[(size_t)r * F_IN + c1] = feat[(size_t)r * F_IN + c1] + D1[i] + b31;
        }
    }
    if (w == 3) {
        const int c2 = 128 + m;
        if (c2 < F_IN) {
            const float b32 = b3[c2];
            #pragma unroll
            for (int i = 0; i < 4; ++i) {
                const int ra = row0 + q * 4 + i;
                const int rb = ra + 16;
                h[(size_t)ra * F_IN + c2] = feat[(size_t)ra * F_IN + c2] + e0[i] + b32;
                h[(size_t)rb * F_IN + c2] = feat[(size_t)rb * F_IN + c2] + e1[i] + b32;
            }
        }
    }
}

// ---------------- kC4: all 4 projections in one block; A staged+packed once ----------------
template<int K, int LDSK, int KC>
__global__ __launch_bounds__(256) void kC4_mf(const float* __restrict__ A,
        const short* __restrict__ WfBase,
        const float* __restrict__ bq, const float* __restrict__ bk,
        const float* __restrict__ bv, const float* __restrict__ bs,
        unsigned short* __restrict__ qh, unsigned short* __restrict__ kh,
        unsigned short* __restrict__ vh, float* __restrict__ sOut) {
    __shared__ float4 sAv[32 * LDSK / 4];
    float* sA = (float*)sAv;
    const int tid = threadIdx.x;
    const int row0 = blockIdx.x * 32;
    for (int idx = tid; idx < 32 * K; idx += 256) {
        int r = idx / K, c = idx - r * K;
        sA[r * LDSK + c] = A[(size_t)(row0 + r) * K + c];
    }
    if (K < KC * 32) {
        const int ZC = KC * 32 - K;
        for (int idx = tid; idx < 32 * ZC; idx += 256) {
            int r = idx / ZC, c = idx - r * ZC;
            sA[r * LDSK + K + c] = 0.f;
        }
    }
    __syncthreads();

    const int lane = tid & 63, w = tid >> 6;
    const int m = lane & 15, q = lane >> 4;
    const int nt0 = w * 2, nt1 = nt0 + 1;

    // pack A-fragments once, keep in registers for all 4 matrices
    v8s afr0[KC], afr1[KC];
    #pragma unroll
    for (int kc = 0; kc < KC; ++kc) {
        const float* r0 = sA + m * LDSK + kc * 32 + q * 8;
        const float* r1 = sA + (16 + m) * LDSK + kc * 32 + q * 8;
        afr0[kc] = pack8(*(const float4*)r0, *(const float4*)(r0 + 4));
        afr1[kc] = pack8(*(const float4*)r1, *(const float4*)(r1 + 4));
    }

    const int c0 = w * 32 + m, c1 = c0 + 16;
    #pragma unroll
    for (int mat = 0; mat < 4; ++mat) {
        const short* Wf = WfBase + (size_t)mat * (KC * 4096);
        const float* bias = (mat == 0) ? bq : (mat == 1) ? bk : (mat == 2) ? bv : bs;
        v4f acc00 = {0.f,0.f,0.f,0.f}, acc01 = acc00, acc10 = acc00, acc11 = acc00;
        #pragma unroll
        for (int kc = 0; kc < KC; ++kc) {
            v8s b0 = *(const v8s*)(Wf + ((size_t)((nt0 * KC + kc) * 64 + lane)) * 8);
            v8s b1 = *(const v8s*)(Wf + ((size_t)((nt1 * KC + kc) * 64 + lane)) * 8);
            acc00 = __builtin_amdgcn_mfma_f32_16x16x32_bf16(afr0[kc], b0, acc00, 0, 0, 0);
            acc01 = __builtin_amdgcn_mfma_f32_16x16x32_bf16(afr0[kc], b1, acc01, 0, 0, 0);
            acc10 = __builtin_amdgcn_mfma_f32_16x16x32_bf16(afr1[kc], b0, acc10, 0, 0, 0);
            acc11 = __builtin_amdgcn_mfma_f32_16x16x32_bf16(afr1[kc], b1, acc11, 0, 0, 0);
        }
        const float b0v = bias[c0], b1v = bias[c1];
        if (mat < 3) {
            unsigned short* outh = (mat == 0) ? qh : (mat == 1) ? kh : vh;
            unsigned short* outw = outh + ((size_t)w * N_NODES + row0) * DHEAD;
            #pragma unroll
            for (int rt = 0; rt < 2; ++rt) {
                v4f A0 = rt ? acc10 : acc00;
                v4f A1 = rt ? acc11 : acc01;
                #pragma unroll
                for (int i = 0; i < 4; ++i) {
                    const int r = rt * 16 + q * 4 + i;
                    outw[(size_t)r * DHEAD + m]      = f2bf(A0[i] + b0v);
                    outw[(size_t)r * DHEAD + 16 + m] = f2bf(A1[i] + b1v);
                }
            }
        } else {
            #pragma unroll
            for (int rt = 0; rt < 2; ++rt) {
                v4f A0 = rt ? acc10 : acc00;
                v4f A1 = rt ? acc11 : acc01;
                #pragma unroll
                for (int i = 0; i < 4; ++i) {
                    const int r = rt * 16 + q * 4 + i;
                    sOut[(size_t)(row0 + r) * HD + c0] = A0[i] + b0v;
                    sOut[(size_t)(row0 + r) * HD + c1] = A1[i] + b1v;
                }
            }
        }
    }
}

// ---------------- kD: head-split attention, bf16 gathers [proven] ----------------
__global__ __launch_bounds__(256) void kD_h(const unsigned short* __restrict__ qh,
        const unsigned short* __restrict__ kh, const unsigned short* __restrict__ vh,
        const int* __restrict__ esrc, float* __restrict__ agg) {
    __shared__ float sk[8][DHEAD];
    __shared__ int ssrc[8][DEG];
    __shared__ float sa[8][DEG];
    const int h = blockIdx.y;
    const int n0 = blockIdx.x * 8;
    const int t = threadIdx.x;
    const int j = t >> 5, e = t & 31;

    ssrc[j][e] = esrc[n0 * DEG + t];
    if (t < 128) {
        unsigned u = *((const unsigned*)(kh + ((size_t)h * N_NODES + n0) * DHEAD) + t);
        float* skf = &sk[0][0];
        skf[2 * t]     = bflo(u);
        skf[2 * t + 1] = bfhi(u);
    }
    __syncthreads();

    const int src = ssrc[j][e];
    const uint4* qp = (const uint4*)(qh + ((size_t)h * N_NODES + src) * DHEAD);
    const float* kj = sk[j];
    float sc = 0.f;
    #pragma unroll
    for (int i = 0; i < 4; ++i) {
        uint4 u = qp[i];
        sc = fmaf(bflo(u.x), kj[i * 8 + 0], sc);
        sc = fmaf(bfhi(u.x), kj[i * 8 + 1], sc);
        sc = fmaf(bflo(u.y), kj[i * 8 + 2], sc);
        sc = fmaf(bfhi(u.y), kj[i * 8 + 3], sc);
        sc = fmaf(bflo(u.z), kj[i * 8 + 4], sc);
        sc = fmaf(bfhi(u.z), kj[i * 8 + 5], sc);
        sc = fmaf(bflo(u.w), kj[i * 8 + 6], sc);
        sc = fmaf(bfhi(u.w), kj[i * 8 + 7], sc);
    }
    sc *= INV_SQRT_D;
    float m = sc;
    #pragma unroll
    for (int off = 16; off > 0; off >>= 1)
        m = fmaxf(m, __shfl_xor(m, off, 32));
    float p = expf(sc - m);
    float ssum = p;
    #pragma unroll
    for (int off = 16; off > 0; off >>= 1)
        ssum += __shfl_xor(ssum, off, 32);
    sa[j][e] = p / ssum;
    __syncthreads();

    const int d = t & 31;
    const unsigned short* vbase = vh + (size_t)h * N_NODES * DHEAD + d;
    float acc = 0.f;
    #pragma unroll
    for (int e2 = 0; e2 < DEG; ++e2) {
        const int s2 = ssrc[j][e2];
        acc = fmaf(bf2f(vbase[(size_t)s2 * DHEAD]), sa[j][e2], acc);
    }
    agg[(size_t)(n0 + j) * HD + h * DHEAD + d] = acc;
}

// ---------------- fast 128-thread block reduce [proven] ----------------
__device__ __forceinline__ float blockSum128(float v, float* s2, int tid) {
    #pragma unroll
    for (int o = 32; o > 0; o >>= 1) v += __shfl_xor(v, o, 64);
    if ((tid & 63) == 0) s2[tid >> 6] = v;
    __syncthreads();
    float r = s2[0] + s2[1];
    __syncthreads();
    return r;
}

// ---------------- kE: gate + gated mix + LayerNorm + PReLU, fp32 [proven] ----------------
__global__ void kE(const float* __restrict__ skip, const float* __restrict__ agg,
                   const float* __restrict__ Wg, const float* __restrict__ bg,
                   const float* __restrict__ lng, const float* __restrict__ lnb,
                   const float* __restrict__ ac,
                   float* __restrict__ hout) {
    __shared__ float red[2];
    int n = blockIdx.x, c = threadIdx.x;
    float sk = skip[n * HD + c], ag = agg[n * HD + c];
    float part = sk * Wg[c] + ag * Wg[HD + c] + (sk - ag) * Wg[2 * HD + c];
    float z = blockSum128(part, red, c) + bg[0];
    float g = 1.f / (1.f + expf(-z));
    float r = g * sk + (1.f - g) * ag;
    float mean = blockSum128(r, red, c) * (1.f / HD);
    float dv = r - mean;
    float var = blockSum128(dv * dv, red, c) * (1.f / HD);
    float y = dv * rsqrtf(var + 1e-5f) * lng[c] + lnb[c];
    float a = ac[0];
    hout[n * HD + c] = (y >= 0.f) ? y : a * y;
}

// ---------------- kF (MFMA, raceless LDS epilogue): out = PReLU(BN(h2@W4+b4)) @ W5 + b5 ----------------
__global__ __launch_bounds__(256) void kF_mf2(const float* __restrict__ A,
        const short* __restrict__ W4f, const float* __restrict__ b4,
        const float* __restrict__ bng, const float* __restrict__ bnb,
        const float* __restrict__ a5, const float* __restrict__ W5,
        const float* __restrict__ b5, float* __restrict__ out) {
    __shared__ float4 sAv[32 * 132 / 4];
    float* sA = (float*)sAv;       // reused as sY after the MFMA phase
    const int tid = threadIdx.x;
    const int row0 = blockIdx.x * 32;
    for (int idx = tid; idx < 32 * HD; idx += 256) {
        int r = idx >> 7, c = idx & 127;
        sA[r * 132 + c] = A[(size_t)(row0 + r) * HD + c];
    }
    __syncthreads();
    const int lane = tid & 63, w = tid >> 6;
    const int m = lane & 15, q = lane >> 4;
    const int nt0 = w * 2, nt1 = nt0 + 1;
    v4f acc00 = {0.f,0.f,0.f,0.f}, acc01 = acc00, acc10 = acc00, acc11 = acc00;
    #pragma unroll
    for (int kc = 0; kc < 4; ++kc) {
        const float* r0 = sA + m * 132 + kc * 32 + q * 8;
        const float* r1 = sA + (16 + m) * 132 + kc * 32 + q * 8;
        v8s a0 = pack8(*(const float4*)r0, *(const float4*)(r0 + 4));
        v8s a1 = pack8(*(const float4*)r1, *(const float4*)(r1 + 4));
        v8s b0 = *(const v8s*)(W4f + ((size_t)((nt0 * 4 + kc) * 64 + lane)) * 8);
        v8s b1 = *(const v8s*)(W4f + ((size_t)((nt1 * 4 + kc) * 64 + lane)) * 8);
        acc00 = __builtin_amdgcn_mfma_f32_16x16x32_bf16(a0, b0, acc00, 0, 0, 0);
        acc01 = __builtin_amdgcn_mfma_f32_16x16x32_bf16(a0, b1, acc01, 0, 0, 0);
        acc10 = __builtin_amdgcn_mfma_f32_16x16x32_bf16(a1, b0, acc10, 0, 0, 0);
        acc11 = __builtin_amdgcn_mfma_f32_16x16x32_bf16(a1, b1, acc11, 0, 0, 0);
    }
    __syncthreads();   // all LDS reads (A) done across the block; safe to overwrite as sY
    const int c0 = w * 32 + m, c1 = c0 + 16;
    const float g0 = bng[c0] * BN_SCALE, g1 = bng[c1] * BN_SCALE;
    const float bb0 = bnb[c0], bb1 = bnb[c1];
    const float b40 = b4[c0], b41 = b4[c1];
    const float al = a5[0];
    #pragma unroll
    for (int rt = 0; rt < 2; ++rt) {
        v4f A0 = rt ? acc10 : acc00;
        v4f A1 = rt ? acc11 : acc01;
        #pragma unroll
        for (int i = 0; i < 4; ++i) {
            const int r = rt * 16 + q * 4 + i;
            float y0 = (A0[i] + b40) * g0 + bb0;
            float y1 = (A1[i] + b41) * g1 + bb1;
            y0 = (y0 >= 0.f) ? y0 : al * y0;
            y1 = (y1 >= 0.f) ? y1 : al * y1;
            sA[r * 132 + c0] = y0;
            sA[r * 132 + c1] = y1;
        }
    }
    __syncthreads();
    if (tid < 64) {
        const int r = tid >> 1, cls = tid & 1;
        const float* yr = sA + r * 132;
        float s = b5[cls];
        #pragma unroll 8
        for (int c = 0; c < HD; ++c)
            s = fmaf(yr[c], W5[c * 2 + cls], s);
        out[(size_t)(row0 + r) * N_CLS + cls] = s;
    }
}

extern "C" void kernel_launch(void* const* d_in, const int* in_sizes, int n_in,
                              void* d_out, int out_size, void* d_ws, size_t ws_size,
                              hipStream_t stream) {
    const float* feat  = (const float*)d_in[0];
    const float* lemb  = (const float*)d_in[1];
    const float* W1    = (const float*)d_in[2];
    const float* b1    = (const float*)d_in[3];
    const float* W2    = (const float*)d_in[4];
    const float* b2    = (const float*)d_in[5];
    const float* bn0g  = (const float*)d_in[6];
    const float* bn0b  = (const float*)d_in[7];
    const float* a3    = (const float*)d_in[8];
    const float* W3    = (const float*)d_in[9];
    const float* b3    = (const float*)d_in[10];
    const float* aconv = (const float*)d_in[35];
    const float* W4    = (const float*)d_in[36];
    const float* b4    = (const float*)d_in[37];
    const float* bn1g  = (const float*)d_in[38];
    const float* bn1b  = (const float*)d_in[39];
    const float* a5    = (const float*)d_in[40];
    const float* W5    = (const float*)d_in[41];
    const float* b5    = (const float*)d_in[42];
    const int*   labels = (const int*)d_in[43];
    const int*   esrc   = (const int*)d_in[44];

    char* ws = (char*)d_ws;
    float* bh  = (float*)ws;                       ws += sizeof(float) * N_NODES * F_IN;
    float* bs  = (float*)ws;                       ws += sizeof(float) * N_NODES * HD;
    float* bag = (float*)ws;                       ws += sizeof(float) * N_NODES * HD;
    float* bh2 = (float*)ws;                       ws += sizeof(float) * N_NODES * HD;
    unsigned short* bqh = (unsigned short*)ws;     ws += sizeof(short) * N_NODES * HD;
    unsigned short* bkh = (unsigned short*)ws;     ws += sizeof(short) * N_NODES * HD;
    unsigned short* bvh = (unsigned short*)ws;     ws += sizeof(short) * N_NODES * HD;
    short* Wf0 = (short*)ws;                       ws += sizeof(short) * 4 * 20480;  // q0,k0,v0,s0
    short* Wf1 = (short*)ws;                       ws += sizeof(short) * 4 * 16384;  // q1,k1,v1,s1
    short* W1f = (short*)ws;                       ws += sizeof(short) * 20480;      // W1
    short* W3f = (short*)ws;                       ws += sizeof(short) * 36 * 512;   // W3
    short* W4f = (short*)ws;                       ws += sizeof(short) * 16384;      // W4
    float* bE = bag;    // E[3][128] lives in bag until first kD_h (proven aliasing)
    float* out = (float*)d_out;

    dim3 gT(N_NODES / 32);
    dim3 gD(N_NODES / 8, NHEAD);

    kE0<<<dim3(3), HD, 0, stream>>>(lemb, W2, b1, b2, bE);
    kSwiz4<5, F_IN><<<dim3(40, 4), 64, 0, stream>>>(
        (const float*)d_in[11], (const float*)d_in[13],
        (const float*)d_in[15], (const float*)d_in[17], Wf0);
    kSwiz4<4, HD><<<dim3(32, 4), 64, 0, stream>>>(
        (const float*)d_in[23], (const float*)d_in[25],
        (const float*)d_in[27], (const float*)d_in[29], Wf1);
    kSwiz1<5, F_IN><<<dim3(40), 64, 0, stream>>>(W1, W1f);
    kSwizW3<<<dim3(36), 64, 0, stream>>>(W3, W3f);
    kSwiz1<4, HD><<<dim3(32), 64, 0, stream>>>(W4, W4f);

    kAB_m<<<gT, 256, 0, stream>>>(feat, W1f, W3f, labels, bE, bn0g, bn0b, a3, b3, bh);

    // conv layer 0 (K=142 -> LDSK=164, KC=5) — merged 4-matrix kC
    kC4_mf<F_IN, 164, 5><<<gT, 256, 0, stream>>>(bh, Wf0,
        (const float*)d_in[12], (const float*)d_in[14],
        (const float*)d_in[16], (const float*)d_in[18],
        bqh, bkh, bvh, bs);
    kD_h<<<gD, 256, 0, stream>>>(bqh, bkh, bvh, esrc, bag);
    kE<<<dim3(N_NODES), HD, 0, stream>>>(bs, bag, (const float*)d_in[19], (const float*)d_in[20],
        (const float*)d_in[21], (const float*)d_in[22], aconv, bh2);

    // conv layer 1 (K=128 -> LDSK=132, KC=4)
    kC4_mf<HD, 132, 4><<<gT, 256, 0, stream>>>(bh2, Wf1,
        (const float*)d_in[24], (const float*)d_in[26],
        (const float*)d_in[28], (const float*)d_in[30],
        bqh, bkh, bvh, bs);
    kD_h<<<gD, 256, 0, stream>>>(bqh, bkh, bvh, esrc, bag);
    kE<<<dim3(N_NODES), HD, 0, stream>>>(bs, bag, (const float*)d_in[31], (const float*)d_in[32],
        (const float*)d_in[33], (const float*)d_in[34], aconv, bh2);

    kF_mf2<<<gT, 256, 0, stream>>>(bh2, W4f, b4, bn1g, bn1b, a5, W5, b5, out);
}